// Round 9
// baseline (163.208 us; speedup 1.0000x reference)
//
#include <hip/hip_runtime.h>
#include <math.h>

#define NPTS 8192
#define KNN  20
#define CHUNK 1024                 // knn: candidates staged per LDS chunk
#define NCHUNK (NPTS / CHUNK)      // 8
#define NCELL 4096                 // 16^3 Morton cells
#define GLO  (-4.0f)
#define GINV (2.0f)

__device__ __forceinline__ int cellof(float v) {
    int c = (int)floorf((v - GLO) * GINV);
    return min(max(c, 0), 15);
}
__device__ __forceinline__ int spread4(int b) {
    return (b & 1) | ((b & 2) << 2) | ((b & 4) << 4) | ((b & 8) << 6);
}

// 64-lane bitonic sort, ascending by lane. Keys d, payload ji.
__device__ __forceinline__ void bitonic64(float& d, int& ji, int lane) {
#pragma unroll
    for (int k = 2; k <= 64; k <<= 1) {
#pragma unroll
        for (int j = k >> 1; j > 0; j >>= 1) {
            const float od = __shfl_xor(d, j);
            const int   oi = __shfl_xor(ji, j);
            const bool up      = ((lane & k) == 0);
            const bool lower   = ((lane & j) == 0);
            const bool takeMin = (up == lower);
            const bool sw = takeMin ? (od < d) : (od > d);
            d  = sw ? od : d;
            ji = sw ? oi : ji;
        }
    }
}

__device__ __forceinline__ void bitonic_clean64(float& d, int& ji, int lane) {
#pragma unroll
    for (int j = 32; j > 0; j >>= 1) {
        const float od = __shfl_xor(d, j);
        const int   oi = __shfl_xor(ji, j);
        const bool lower = ((lane & j) == 0);
        const bool sw = lower ? (od < d) : (od > d);
        d  = sw ? od : d;
        ji = sw ? oi : ji;
    }
}

// merge LDS hit-pool (cnt entries) into the resident sorted-64 list (ld,lj)
__device__ __forceinline__ void compact(float& ld, int& lj,
                                        const float* __restrict__ sd,
                                        const int* __restrict__ sj,
                                        int cnt, int lane) {
    __builtin_amdgcn_wave_barrier();          // order pool ds_writes before reads
    float bd = (lane < cnt) ? sd[lane] : INFINITY;
    int   bj = (lane < cnt) ? sj[lane] : -1;
    bitonic64(bd, bj, lane);
    const float rd = __shfl(bd, 63 - lane);
    const int   rj = __shfl(bj, 63 - lane);
    const bool sw = rd < ld;
    float md = sw ? rd : ld;
    int   mj = sw ? rj : lj;
    bitonic_clean64(md, mj, lane);
    ld = md; lj = mj;
}

// ---------------- fused prep: xq + Morton cell id + hist + Wc0/1/2 ----------------
__device__ __forceinline__ void prep_w_elem(const float* __restrict__ W,
                                            float* __restrict__ Wc,
                                            int tid, int O, int C) {
    const int o = tid / C, k = tid % C;
    const float wa = W[o*2*C + k];
    const float wb = W[o*2*C + C + k];
    Wc[o*C + k]       = wa - wb;
    Wc[(O + o)*C + k] = wb;
}

__global__ void prep_all(const float* __restrict__ x,
                         const float* __restrict__ W0,
                         const float* __restrict__ W1,
                         const float* __restrict__ W2,
                         float4* __restrict__ xq,
                         int* __restrict__ bId,
                         int* __restrict__ hist,
                         float* __restrict__ Wc0,
                         float* __restrict__ Wc1,
                         float* __restrict__ Wc2) {
    const int bid = blockIdx.x;
    const int t = threadIdx.x;
    if (bid < 32) {
        const int i = bid * 256 + t;
        const float a = x[3*i+0], b = x[3*i+1], c = x[3*i+2];
        xq[i] = make_float4(a, b, c, 0.0f);
        const int cell = spread4(cellof(a)) | (spread4(cellof(b)) << 1)
                       | (spread4(cellof(c)) << 2);
        bId[i] = cell;
        atomicAdd(&hist[cell], 1);
    } else if (bid == 32) {
        if (t < 192) prep_w_elem(W0, Wc0, t, 64, 3);
    } else if (bid < 65) {
        prep_w_elem(W1, Wc1, (bid - 33) * 256 + t, 128, 64);
    } else {
        prep_w_elem(W2, Wc2, (bid - 65) * 256 + t, 256, 128);
    }
}

// ---------------- exclusive prefix over 4096 cells (1 block, 4/thread) ----------------
__global__ __launch_bounds__(1024) void prefix4096(const int* __restrict__ hist,
                                                   int* __restrict__ work) {
    __shared__ int s[1024];
    const int t = threadIdx.x;
    const int4 v = *reinterpret_cast<const int4*>(&hist[t * 4]);
    const int s0 = v.x, s1 = s0 + v.y, s2 = s1 + v.z, s3 = s2 + v.w;
    s[t] = s3;
    __syncthreads();
    for (int off = 1; off < 1024; off <<= 1) {
        const int u = (t >= off) ? s[t - off] : 0;
        __syncthreads();
        s[t] += u;
        __syncthreads();
    }
    const int excl = s[t] - s3;
    work[t*4+0] = excl;
    work[t*4+1] = excl + s0;
    work[t*4+2] = excl + s1;
    work[t*4+3] = excl + s2;
}

// ---------------- per-point scatter into Morton-sorted order ----------------
__global__ __launch_bounds__(256) void scatter_pts(const float4* __restrict__ xq,
                                                   const int* __restrict__ bId,
                                                   int* __restrict__ work,
                                                   float4* __restrict__ srt) {
    const int i = blockIdx.x * 256 + threadIdx.x;
    const int pos = atomicAdd(&work[bId[i]], 1);
    float4 v = xq[i];
    v.w = __int_as_float(i);
    srt[pos] = v;
}

// ---------------- KNN: Morton-ordered brute force ----------------
// 1 query/wave (wave = sorted position s), 4 waves/block. Init top-64 from the
// query's OWN sorted 64-block -> Morton-local -> cm_init ~ true r21 -> the
// full scan (all 8192, staged via 16 KB LDS chunks, 4-batch ILP) almost never
// hits; ~20-40 pool appends + 1-2 compacts total. Exact: lazy cm >= true r21.
// Output lanes 1..20 (lane 0 = self, d=0); indices are ORIGINAL ids (srt.w).
__global__ __launch_bounds__(256) void knn_kernel(const float4* __restrict__ srt,
                                                  int* __restrict__ idx_out) {
    __shared__ float4 sxq[CHUNK];
    __shared__ float  sdp[4][64];
    __shared__ int    sjp[4][64];
    const int lane = threadIdx.x & 63;
    const int wv   = threadIdx.x >> 6;
    const int s    = blockIdx.x * 4 + wv;
    float* sd = sdp[wv];
    int*   sj = sjp[wv];

    const float4 p = srt[s];
    const int qorig = __float_as_int(p.w);
    const int base = s & ~63;                 // own sorted 64-block

    // init: own Morton block (contains self, d=0 -> lane 0 after sort)
    float ld, cm;
    int lj;
    {
        const float4 c = srt[base + lane];
        const float dx = p.x - c.x, dy = p.y - c.y, dz = p.z - c.z;
        ld = dx*dx + dy*dy + dz*dz;
        lj = __float_as_int(c.w);
        bitonic64(ld, lj, lane);
        cm = __shfl(ld, KNN);                 // 21st incl self = 20th excl
    }
    int cnt = 0;

    for (int c = 0; c < NCHUNK; ++c) {
        __syncthreads();   // protect previous chunk's reads
#pragma unroll
        for (int u = 0; u < CHUNK / 256; ++u)
            sxq[u * 256 + threadIdx.x] = srt[c * CHUNK + u * 256 + threadIdx.x];
        __syncthreads();

        const int cbase = c * CHUNK;
        for (int g = 0; g < 4; ++g) {         // 4 groups x 4 batches x 64
            const int b0 = g * 4;
            const float4 c0 = sxq[(b0+0)*64 + lane];
            const float4 c1 = sxq[(b0+1)*64 + lane];
            const float4 c2 = sxq[(b0+2)*64 + lane];
            const float4 c3 = sxq[(b0+3)*64 + lane];
            const float dx0 = p.x-c0.x, dy0 = p.y-c0.y, dz0 = p.z-c0.z;
            const float dx1 = p.x-c1.x, dy1 = p.y-c1.y, dz1 = p.z-c1.z;
            const float dx2 = p.x-c2.x, dy2 = p.y-c2.y, dz2 = p.z-c2.z;
            const float dx3 = p.x-c3.x, dy3 = p.y-c3.y, dz3 = p.z-c3.z;
            const float d0 = dx0*dx0 + dy0*dy0 + dz0*dz0;
            const float d1 = dx1*dx1 + dy1*dy1 + dz1*dz1;
            const float d2 = dx2*dx2 + dy2*dy2 + dz2*dz2;
            const float d3 = dx3*dx3 + dy3*dy3 + dz3*dz3;
            const int jb0 = cbase + (b0+0)*64;
            unsigned long long m0 = __ballot(d0 < cm);
            unsigned long long m1 = __ballot(d1 < cm);
            unsigned long long m2 = __ballot(d2 < cm);
            unsigned long long m3 = __ballot(d3 < cm);
            if (jb0 == base) m0 = 0;          // own block already in init
            if (jb0 + 64  == base) m1 = 0;
            if (jb0 + 128 == base) m2 = 0;
            if (jb0 + 192 == base) m3 = 0;
            if (m0 | m1 | m2 | m3) {
#define HANDLE(M, D, C4)                                                      \
                if (M) {                                                      \
                    const int tot = __popcll(M);                              \
                    if (cnt + tot > 64) {                                     \
                        compact(ld, lj, sd, sj, cnt, lane);                   \
                        cm = __shfl(ld, KNN);                                 \
                        cnt = 0;                                              \
                    }                                                         \
                    const int below = __builtin_amdgcn_mbcnt_hi(              \
                        (unsigned)((M) >> 32),                                \
                        __builtin_amdgcn_mbcnt_lo((unsigned)(M), 0));         \
                    const bool h = ((M) >> lane) & 1ull;                      \
                    if (h) { sd[cnt + below] = D; sj[cnt + below] = __float_as_int(C4.w); } \
                    cnt += tot;                                               \
                }
                HANDLE(m0, d0, c0)
                HANDLE(m1, d1, c1)
                HANDLE(m2, d2, c2)
                HANDLE(m3, d3, c3)
#undef HANDLE
            }
        }
    }
    if (cnt > 0) compact(ld, lj, sd, sj, cnt, lane);

    if (lane >= 1 && lane <= KNN) idx_out[qorig * KNN + lane - 1] = lj;
}

// ---------------- layer0 GEMM: K=3 special case ----------------
__global__ __launch_bounds__(128) void gemm0_kernel(const float* __restrict__ x,
                                                    const float* __restrict__ Wc,
                                                    float* __restrict__ T) {
    __shared__ float sw[384];
    const int t = threadIdx.x;
    sw[t]       = Wc[t];
    sw[t + 128] = Wc[t + 128];
    sw[t + 256] = Wc[t + 256];
    __syncthreads();
    const int n = blockIdx.x;
    const float x0 = x[3*n+0], x1 = x[3*n+1], x2 = x[3*n+2];
    T[n*128 + t] = x0*sw[3*t+0] + x1*sw[3*t+1] + x2*sw[3*t+2];
}

// ---------------- fp32 GEMM: T = H (NxK) * W^T (MxK) ----------------
#define BK 16
__global__ __launch_bounds__(256) void gemm_nt(const float* __restrict__ H,
                                               const float* __restrict__ W,
                                               float* __restrict__ T,
                                               int Kk, int Mm) {
    __shared__ float sH[BK][132];
    __shared__ float sW[BK][68];
    const int t  = threadIdx.x;
    const int rg = t & 15;
    const int cg = t >> 4;
    const int row0 = blockIdx.x * 128;
    const int col0 = blockIdx.y * 64;

    const int ar = t >> 2;
    const int ac = t & 3;

    float acc[8][4];
#pragma unroll
    for (int r = 0; r < 8; ++r)
#pragma unroll
        for (int c = 0; c < 4; ++c) acc[r][c] = 0.0f;

    for (int k0 = 0; k0 < Kk; k0 += BK) {
        const float4 ha = *reinterpret_cast<const float4*>(&H[(row0 + ar)      * Kk + k0 + ac*4]);
        const float4 hb = *reinterpret_cast<const float4*>(&H[(row0 + 64 + ar) * Kk + k0 + ac*4]);
        const float4 wa = *reinterpret_cast<const float4*>(&W[(col0 + ar)      * Kk + k0 + ac*4]);
        __syncthreads();
        sH[ac*4+0][ar]    = ha.x; sH[ac*4+1][ar]    = ha.y; sH[ac*4+2][ar]    = ha.z; sH[ac*4+3][ar]    = ha.w;
        sH[ac*4+0][64+ar] = hb.x; sH[ac*4+1][64+ar] = hb.y; sH[ac*4+2][64+ar] = hb.z; sH[ac*4+3][64+ar] = hb.w;
        sW[ac*4+0][ar]    = wa.x; sW[ac*4+1][ar]    = wa.y; sW[ac*4+2][ar]    = wa.z; sW[ac*4+3][ar]    = wa.w;
        __syncthreads();
#pragma unroll
        for (int kk = 0; kk < BK; ++kk) {
            const float4 a0 = *reinterpret_cast<const float4*>(&sH[kk][rg*4]);
            const float4 a1 = *reinterpret_cast<const float4*>(&sH[kk][64 + rg*4]);
            const float4 bv = *reinterpret_cast<const float4*>(&sW[kk][cg*4]);
            const float arr[8] = {a0.x, a0.y, a0.z, a0.w, a1.x, a1.y, a1.z, a1.w};
            const float bb[4]  = {bv.x, bv.y, bv.z, bv.w};
#pragma unroll
            for (int r = 0; r < 8; ++r)
#pragma unroll
                for (int c = 0; c < 4; ++c)
                    acc[r][c] = fmaf(arr[r], bb[c], acc[r][c]);
        }
    }
#pragma unroll
    for (int r = 0; r < 8; ++r) {
        const int row = (r < 4) ? (rg*4 + r) : (64 + rg*4 + (r - 4));
        *reinterpret_cast<float4*>(&T[(row0 + row)*Mm + col0 + cg*4]) =
            make_float4(acc[r][0], acc[r][1], acc[r][2], acc[r][3]);
    }
}

// ---------------- gather + max + bias + relu (float4 per thread) ----------------
// Q = O/4 quad-threads per point; PPB = 256/Q points per block.
template<int O>
__global__ __launch_bounds__(256) void maxrelu_kernel(const float* __restrict__ T,
                                                      const int* __restrict__ idx,
                                                      const float* __restrict__ bias,
                                                      float* __restrict__ out) {
    constexpr int Q   = O / 4;
    constexpr int PPB = 256 / Q;
    constexpr int M2  = 2 * O;
    const int pi = threadIdx.x / Q;
    const int oq = threadIdx.x & (Q - 1);
    const int i  = blockIdx.x * PPB + pi;
    __shared__ int sidx[PPB * KNN];
    for (int t = threadIdx.x; t < PPB * KNN; t += 256)
        sidx[t] = idx[blockIdx.x * PPB * KNN + t];
    __syncthreads();
    const int sb = pi * KNN;
    float4 m = make_float4(-INFINITY, -INFINITY, -INFINITY, -INFINITY);
#pragma unroll
    for (int k = 0; k < KNN; ++k) {
        const float4 v = *reinterpret_cast<const float4*>(&T[sidx[sb + k] * M2 + O + oq * 4]);
        m.x = fmaxf(m.x, v.x); m.y = fmaxf(m.y, v.y);
        m.z = fmaxf(m.z, v.z); m.w = fmaxf(m.w, v.w);
    }
    const float4 b = *reinterpret_cast<const float4*>(&T[i * M2 + oq * 4]);
    const float4 bv = *reinterpret_cast<const float4*>(&bias[oq * 4]);
    float4 o;
    o.x = fmaxf(b.x + bv.x + m.x, 0.0f);
    o.y = fmaxf(b.y + bv.y + m.y, 0.0f);
    o.z = fmaxf(b.z + bv.z + m.z, 0.0f);
    o.w = fmaxf(b.w + bv.w + m.w, 0.0f);
    *reinterpret_cast<float4*>(&out[i * O + oq * 4]) = o;
}

extern "C" void kernel_launch(void* const* d_in, const int* in_sizes, int n_in,
                              void* d_out, int out_size, void* d_ws, size_t ws_size,
                              hipStream_t stream) {
    const float* x  = (const float*)d_in[0];
    const float* W0 = (const float*)d_in[1];
    const float* b0 = (const float*)d_in[2];
    const float* W1 = (const float*)d_in[3];
    const float* b1 = (const float*)d_in[4];
    const float* W2 = (const float*)d_in[5];
    const float* b2 = (const float*)d_in[6];
    float* out = (float*)d_out;
    char*  ws  = (char*)d_ws;

    int*   idx  = (int*)(ws + 0);                 // 655360
    float* Wc0  = (float*)(ws + 655360);          // 1536
    float* Wc1  = (float*)(ws + 656896);          // 65536
    float* Wc2  = (float*)(ws + 722432);          // 262144
    float* bufA = (float*)(ws + 984576);          // 16 MB
    float* bufB = (float*)(ws + 17761792);        // 4 MB

    // knn-phase scratch aliases bufA (dead before gemm0 writes bufA)
    float4* xq   = (float4*)bufA;                       // 128 KB
    float4* srt  = (float4*)((char*)bufA + 131072);     // 128 KB
    int*    bId  = (int*)((char*)bufA + 262144);        // 32 KB
    int*    hist = (int*)((char*)bufA + 294912);        // 16 KB
    int*    work = (int*)((char*)bufA + 311296);        // 16 KB

    hipMemsetAsync(hist, 0, NCELL * sizeof(int), stream);
    prep_all<<<193, 256, 0, stream>>>(x, W0, W1, W2, xq, bId, hist, Wc0, Wc1, Wc2);
    prefix4096<<<1, 1024, 0, stream>>>(hist, work);
    scatter_pts<<<32, 256, 0, stream>>>(xq, bId, work, srt);
    knn_kernel<<<NPTS / 4, 256, 0, stream>>>(srt, idx);

    gemm0_kernel<<<NPTS, 128, 0, stream>>>(x, Wc0, bufA);
    maxrelu_kernel<64><<<NPTS / 16, 256, 0, stream>>>(bufA, idx, b0, bufB);

    gemm_nt<<<dim3(64, 4), 256, 0, stream>>>(bufB, Wc1, bufA, 64, 256);
    maxrelu_kernel<128><<<NPTS / 8, 256, 0, stream>>>(bufA, idx, b1, bufB);

    gemm_nt<<<dim3(64, 8), 256, 0, stream>>>(bufB, Wc2, bufA, 128, 512);
    maxrelu_kernel<256><<<NPTS / 4, 256, 0, stream>>>(bufA, idx, b2, out);
}

// Round 10
// 138.635 us; speedup vs baseline: 1.1772x; 1.1772x over previous
//
#include <hip/hip_runtime.h>
#include <math.h>

#define NPTS 8192
#define KNN  20
#define CHUNK 1024                 // knn: candidates staged per LDS chunk
#define NCHUNK (NPTS / CHUNK)      // 8
#define NBLK (NPTS / 64)           // 128 sorted 64-blocks
#define NCELL 4096                 // 16^3 Morton cells
#define GLO  (-4.0f)
#define GINV (2.0f)

__device__ __forceinline__ int cellof(float v) {
    int c = (int)floorf((v - GLO) * GINV);
    return min(max(c, 0), 15);
}
__device__ __forceinline__ int spread4(int b) {
    return (b & 1) | ((b & 2) << 2) | ((b & 4) << 4) | ((b & 8) << 6);
}

// 64-lane bitonic sort, ascending by lane. Keys d, payload ji.
__device__ __forceinline__ void bitonic64(float& d, int& ji, int lane) {
#pragma unroll
    for (int k = 2; k <= 64; k <<= 1) {
#pragma unroll
        for (int j = k >> 1; j > 0; j >>= 1) {
            const float od = __shfl_xor(d, j);
            const int   oi = __shfl_xor(ji, j);
            const bool up      = ((lane & k) == 0);
            const bool lower   = ((lane & j) == 0);
            const bool takeMin = (up == lower);
            const bool sw = takeMin ? (od < d) : (od > d);
            d  = sw ? od : d;
            ji = sw ? oi : ji;
        }
    }
}

__device__ __forceinline__ void bitonic_clean64(float& d, int& ji, int lane) {
#pragma unroll
    for (int j = 32; j > 0; j >>= 1) {
        const float od = __shfl_xor(d, j);
        const int   oi = __shfl_xor(ji, j);
        const bool lower = ((lane & j) == 0);
        const bool sw = lower ? (od < d) : (od > d);
        d  = sw ? od : d;
        ji = sw ? oi : ji;
    }
}

// merge LDS hit-pool (cnt entries) into the resident sorted-64 list (ld,lj)
__device__ __forceinline__ void compact(float& ld, int& lj,
                                        const float* __restrict__ sd,
                                        const int* __restrict__ sj,
                                        int cnt, int lane) {
    __builtin_amdgcn_wave_barrier();          // order pool ds_writes before reads
    float bd = (lane < cnt) ? sd[lane] : INFINITY;
    int   bj = (lane < cnt) ? sj[lane] : -1;
    bitonic64(bd, bj, lane);
    const float rd = __shfl(bd, 63 - lane);
    const int   rj = __shfl(bj, 63 - lane);
    const bool sw = rd < ld;
    float md = sw ? rd : ld;
    int   mj = sw ? rj : lj;
    bitonic_clean64(md, mj, lane);
    ld = md; lj = mj;
}

// ---------------- fused prep: xq + Morton cell id + hist + Wc0/1/2 ----------------
__device__ __forceinline__ void prep_w_elem(const float* __restrict__ W,
                                            float* __restrict__ Wc,
                                            int tid, int O, int C) {
    const int o = tid / C, k = tid % C;
    const float wa = W[o*2*C + k];
    const float wb = W[o*2*C + C + k];
    Wc[o*C + k]       = wa - wb;
    Wc[(O + o)*C + k] = wb;
}

__global__ void prep_all(const float* __restrict__ x,
                         const float* __restrict__ W0,
                         const float* __restrict__ W1,
                         const float* __restrict__ W2,
                         float4* __restrict__ xq,
                         int* __restrict__ bId,
                         int* __restrict__ hist,
                         float* __restrict__ Wc0,
                         float* __restrict__ Wc1,
                         float* __restrict__ Wc2) {
    const int bid = blockIdx.x;
    const int t = threadIdx.x;
    if (bid < 32) {
        const int i = bid * 256 + t;
        const float a = x[3*i+0], b = x[3*i+1], c = x[3*i+2];
        xq[i] = make_float4(a, b, c, 0.0f);
        const int cell = spread4(cellof(a)) | (spread4(cellof(b)) << 1)
                       | (spread4(cellof(c)) << 2);
        bId[i] = cell;
        atomicAdd(&hist[cell], 1);
    } else if (bid == 32) {
        if (t < 192) prep_w_elem(W0, Wc0, t, 64, 3);
    } else if (bid < 65) {
        prep_w_elem(W1, Wc1, (bid - 33) * 256 + t, 128, 64);
    } else {
        prep_w_elem(W2, Wc2, (bid - 65) * 256 + t, 256, 128);
    }
}

// ---------------- exclusive prefix over 4096 cells (1 block, 4/thread) ----------------
__global__ __launch_bounds__(1024) void prefix4096(const int* __restrict__ hist,
                                                   int* __restrict__ work) {
    __shared__ int s[1024];
    const int t = threadIdx.x;
    const int4 v = *reinterpret_cast<const int4*>(&hist[t * 4]);
    const int s0 = v.x, s1 = s0 + v.y, s2 = s1 + v.z, s3 = s2 + v.w;
    s[t] = s3;
    __syncthreads();
    for (int off = 1; off < 1024; off <<= 1) {
        const int u = (t >= off) ? s[t - off] : 0;
        __syncthreads();
        s[t] += u;
        __syncthreads();
    }
    const int excl = s[t] - s3;
    work[t*4+0] = excl;
    work[t*4+1] = excl + s0;
    work[t*4+2] = excl + s1;
    work[t*4+3] = excl + s2;
}

// ---------------- per-point scatter into Morton-sorted order ----------------
__global__ __launch_bounds__(256) void scatter_pts(const float4* __restrict__ xq,
                                                   const int* __restrict__ bId,
                                                   int* __restrict__ work,
                                                   float4* __restrict__ srt) {
    const int i = blockIdx.x * 256 + threadIdx.x;
    const int pos = atomicAdd(&work[bId[i]], 1);
    float4 v = xq[i];
    v.w = __int_as_float(i);
    srt[pos] = v;
}

// ---------------- KNN: Morton-ordered brute force + window pre-pass ----------------
// 1 query/wave (wave = sorted position s). Init top-64 from own sorted block;
// PRE-PASS over Morton window [bq-3, bq+3] (direct L2 reads) tightens cm to
// ~true r21 for ALL queries (kills edge-query stragglers: a ball of radius r21
// holds ~21 points, so the main scan hits ~21x per query). Window excluded
// from main scan (scalar block-range test; also prevents duplicate appends).
// Main scan: full 8192 via 16 KB LDS chunks, 4-batch ILP. Exact (lazy cm >=
// true r21; strict < ; ties measure-zero). Output lanes 1..20, original ids.
__global__ __launch_bounds__(256) void knn_kernel(const float4* __restrict__ srt,
                                                  int* __restrict__ idx_out) {
    __shared__ float4 sxq[CHUNK];
    __shared__ float  sdp[4][64];
    __shared__ int    sjp[4][64];
    const int lane = threadIdx.x & 63;
    const int wv   = threadIdx.x >> 6;
    const int s    = blockIdx.x * 4 + wv;
    float* sd = sdp[wv];
    int*   sj = sjp[wv];

    const float4 p = srt[s];
    const int qorig = __float_as_int(p.w);
    const int bq = s >> 6;                    // own sorted 64-block index

    // init: own Morton block (contains self, d=0 -> lane 0 after final sort)
    float ld, cm;
    int lj;
    {
        const float4 c = srt[(bq << 6) + lane];
        const float dx = p.x - c.x, dy = p.y - c.y, dz = p.z - c.z;
        ld = dx*dx + dy*dy + dz*dz;
        lj = __float_as_int(c.w);
        bitonic64(ld, lj, lane);
        cm = __shfl(ld, KNN);                 // 21st incl self = 20th excl
    }
    int cnt = 0;

#define APPEND(M, D, C4)                                                      \
    if (M) {                                                                  \
        const int tot = __popcll(M);                                          \
        if (cnt + tot > 64) {                                                 \
            compact(ld, lj, sd, sj, cnt, lane);                               \
            cm = __shfl(ld, KNN);                                             \
            cnt = 0;                                                          \
        }                                                                     \
        const int below = __builtin_amdgcn_mbcnt_hi(                          \
            (unsigned)((M) >> 32),                                            \
            __builtin_amdgcn_mbcnt_lo((unsigned)(M), 0));                     \
        const bool h = ((M) >> lane) & 1ull;                                  \
        if (h) { sd[cnt + below] = D; sj[cnt + below] = __float_as_int(C4.w); } \
        cnt += tot;                                                           \
    }

    // pre-pass: Morton window (direct from L2), excluding own block
    const int wlo = max(bq - 3, 0);
    const int whi = min(bq + 3, NBLK - 1);
    for (int bb = wlo; bb <= whi; ++bb) {
        if (bb == bq) continue;
        const float4 pc = srt[(bb << 6) + lane];
        const float dx = p.x - pc.x, dy = p.y - pc.y, dz = p.z - pc.z;
        const float d = dx*dx + dy*dy + dz*dz;
        const unsigned long long m = __ballot(d < cm);
        APPEND(m, d, pc)
    }
    if (cnt > 0) { compact(ld, lj, sd, sj, cnt, lane); cm = __shfl(ld, KNN); cnt = 0; }

    // main scan over all chunks, skipping window blocks [wlo, whi]
    for (int c = 0; c < NCHUNK; ++c) {
        __syncthreads();   // protect previous chunk's reads
#pragma unroll
        for (int u = 0; u < CHUNK / 256; ++u)
            sxq[u * 256 + threadIdx.x] = srt[c * CHUNK + u * 256 + threadIdx.x];
        __syncthreads();

        const int cblk = c * (CHUNK / 64);    // first block index of this chunk
        for (int g = 0; g < 4; ++g) {         // 4 groups x 4 batches x 64
            const int b0 = g * 4;
            const float4 c0 = sxq[(b0+0)*64 + lane];
            const float4 c1 = sxq[(b0+1)*64 + lane];
            const float4 c2 = sxq[(b0+2)*64 + lane];
            const float4 c3 = sxq[(b0+3)*64 + lane];
            const float dx0 = p.x-c0.x, dy0 = p.y-c0.y, dz0 = p.z-c0.z;
            const float dx1 = p.x-c1.x, dy1 = p.y-c1.y, dz1 = p.z-c1.z;
            const float dx2 = p.x-c2.x, dy2 = p.y-c2.y, dz2 = p.z-c2.z;
            const float dx3 = p.x-c3.x, dy3 = p.y-c3.y, dz3 = p.z-c3.z;
            const float d0 = dx0*dx0 + dy0*dy0 + dz0*dz0;
            const float d1 = dx1*dx1 + dy1*dy1 + dz1*dz1;
            const float d2 = dx2*dx2 + dy2*dy2 + dz2*dz2;
            const float d3 = dx3*dx3 + dy3*dy3 + dz3*dz3;
            unsigned long long m0 = __ballot(d0 < cm);
            unsigned long long m1 = __ballot(d1 < cm);
            unsigned long long m2 = __ballot(d2 < cm);
            unsigned long long m3 = __ballot(d3 < cm);
            const int bb0 = cblk + b0;
            if (bb0     >= wlo && bb0     <= whi) m0 = 0;   // window done in pre-pass
            if (bb0 + 1 >= wlo && bb0 + 1 <= whi) m1 = 0;
            if (bb0 + 2 >= wlo && bb0 + 2 <= whi) m2 = 0;
            if (bb0 + 3 >= wlo && bb0 + 3 <= whi) m3 = 0;
            if (m0 | m1 | m2 | m3) {
                APPEND(m0, d0, c0)
                APPEND(m1, d1, c1)
                APPEND(m2, d2, c2)
                APPEND(m3, d3, c3)
            }
        }
    }
    if (cnt > 0) compact(ld, lj, sd, sj, cnt, lane);
#undef APPEND

    if (lane >= 1 && lane <= KNN) idx_out[qorig * KNN + lane - 1] = lj;
}

// ---------------- layer0 GEMM: K=3 special case ----------------
__global__ __launch_bounds__(128) void gemm0_kernel(const float* __restrict__ x,
                                                    const float* __restrict__ Wc,
                                                    float* __restrict__ T) {
    __shared__ float sw[384];
    const int t = threadIdx.x;
    sw[t]       = Wc[t];
    sw[t + 128] = Wc[t + 128];
    sw[t + 256] = Wc[t + 256];
    __syncthreads();
    const int n = blockIdx.x;
    const float x0 = x[3*n+0], x1 = x[3*n+1], x2 = x[3*n+2];
    T[n*128 + t] = x0*sw[3*t+0] + x1*sw[3*t+1] + x2*sw[3*t+2];
}

// ---------------- fp32 GEMM: T = H (NxK) * W^T (MxK) ----------------
#define BK 16
__global__ __launch_bounds__(256) void gemm_nt(const float* __restrict__ H,
                                               const float* __restrict__ W,
                                               float* __restrict__ T,
                                               int Kk, int Mm) {
    __shared__ float sH[BK][132];
    __shared__ float sW[BK][68];
    const int t  = threadIdx.x;
    const int rg = t & 15;
    const int cg = t >> 4;
    const int row0 = blockIdx.x * 128;
    const int col0 = blockIdx.y * 64;

    const int ar = t >> 2;
    const int ac = t & 3;

    float acc[8][4];
#pragma unroll
    for (int r = 0; r < 8; ++r)
#pragma unroll
        for (int c = 0; c < 4; ++c) acc[r][c] = 0.0f;

    for (int k0 = 0; k0 < Kk; k0 += BK) {
        const float4 ha = *reinterpret_cast<const float4*>(&H[(row0 + ar)      * Kk + k0 + ac*4]);
        const float4 hb = *reinterpret_cast<const float4*>(&H[(row0 + 64 + ar) * Kk + k0 + ac*4]);
        const float4 wa = *reinterpret_cast<const float4*>(&W[(col0 + ar)      * Kk + k0 + ac*4]);
        __syncthreads();
        sH[ac*4+0][ar]    = ha.x; sH[ac*4+1][ar]    = ha.y; sH[ac*4+2][ar]    = ha.z; sH[ac*4+3][ar]    = ha.w;
        sH[ac*4+0][64+ar] = hb.x; sH[ac*4+1][64+ar] = hb.y; sH[ac*4+2][64+ar] = hb.z; sH[ac*4+3][64+ar] = hb.w;
        sW[ac*4+0][ar]    = wa.x; sW[ac*4+1][ar]    = wa.y; sW[ac*4+2][ar]    = wa.z; sW[ac*4+3][ar]    = wa.w;
        __syncthreads();
#pragma unroll
        for (int kk = 0; kk < BK; ++kk) {
            const float4 a0 = *reinterpret_cast<const float4*>(&sH[kk][rg*4]);
            const float4 a1 = *reinterpret_cast<const float4*>(&sH[kk][64 + rg*4]);
            const float4 bv = *reinterpret_cast<const float4*>(&sW[kk][cg*4]);
            const float arr[8] = {a0.x, a0.y, a0.z, a0.w, a1.x, a1.y, a1.z, a1.w};
            const float bb[4]  = {bv.x, bv.y, bv.z, bv.w};
#pragma unroll
            for (int r = 0; r < 8; ++r)
#pragma unroll
                for (int c = 0; c < 4; ++c)
                    acc[r][c] = fmaf(arr[r], bb[c], acc[r][c]);
        }
    }
#pragma unroll
    for (int r = 0; r < 8; ++r) {
        const int row = (r < 4) ? (rg*4 + r) : (64 + rg*4 + (r - 4));
        *reinterpret_cast<float4*>(&T[(row0 + row)*Mm + col0 + cg*4]) =
            make_float4(acc[r][0], acc[r][1], acc[r][2], acc[r][3]);
    }
}

// ---------------- gather + max + bias + relu (float4 per thread) ----------------
template<int O>
__global__ __launch_bounds__(256) void maxrelu_kernel(const float* __restrict__ T,
                                                      const int* __restrict__ idx,
                                                      const float* __restrict__ bias,
                                                      float* __restrict__ out) {
    constexpr int Q   = O / 4;
    constexpr int PPB = 256 / Q;
    constexpr int M2  = 2 * O;
    const int pi = threadIdx.x / Q;
    const int oq = threadIdx.x & (Q - 1);
    const int i  = blockIdx.x * PPB + pi;
    __shared__ int sidx[PPB * KNN];
    for (int t = threadIdx.x; t < PPB * KNN; t += 256)
        sidx[t] = idx[blockIdx.x * PPB * KNN + t];
    __syncthreads();
    const int sb = pi * KNN;
    float4 m = make_float4(-INFINITY, -INFINITY, -INFINITY, -INFINITY);
#pragma unroll
    for (int k = 0; k < KNN; ++k) {
        const float4 v = *reinterpret_cast<const float4*>(&T[sidx[sb + k] * M2 + O + oq * 4]);
        m.x = fmaxf(m.x, v.x); m.y = fmaxf(m.y, v.y);
        m.z = fmaxf(m.z, v.z); m.w = fmaxf(m.w, v.w);
    }
    const float4 b = *reinterpret_cast<const float4*>(&T[i * M2 + oq * 4]);
    const float4 bv = *reinterpret_cast<const float4*>(&bias[oq * 4]);
    float4 o;
    o.x = fmaxf(b.x + bv.x + m.x, 0.0f);
    o.y = fmaxf(b.y + bv.y + m.y, 0.0f);
    o.z = fmaxf(b.z + bv.z + m.z, 0.0f);
    o.w = fmaxf(b.w + bv.w + m.w, 0.0f);
    *reinterpret_cast<float4*>(&out[i * O + oq * 4]) = o;
}

extern "C" void kernel_launch(void* const* d_in, const int* in_sizes, int n_in,
                              void* d_out, int out_size, void* d_ws, size_t ws_size,
                              hipStream_t stream) {
    const float* x  = (const float*)d_in[0];
    const float* W0 = (const float*)d_in[1];
    const float* b0 = (const float*)d_in[2];
    const float* W1 = (const float*)d_in[3];
    const float* b1 = (const float*)d_in[4];
    const float* W2 = (const float*)d_in[5];
    const float* b2 = (const float*)d_in[6];
    float* out = (float*)d_out;
    char*  ws  = (char*)d_ws;

    int*   idx  = (int*)(ws + 0);                 // 655360
    float* Wc0  = (float*)(ws + 655360);          // 1536
    float* Wc1  = (float*)(ws + 656896);          // 65536
    float* Wc2  = (float*)(ws + 722432);          // 262144
    float* bufA = (float*)(ws + 984576);          // 16 MB
    float* bufB = (float*)(ws + 17761792);        // 4 MB

    // knn-phase scratch aliases bufA (dead before gemm0 writes bufA)
    float4* xq   = (float4*)bufA;                       // 128 KB
    float4* srt  = (float4*)((char*)bufA + 131072);     // 128 KB
    int*    bId  = (int*)((char*)bufA + 262144);        // 32 KB
    int*    hist = (int*)((char*)bufA + 294912);        // 16 KB
    int*    work = (int*)((char*)bufA + 311296);        // 16 KB

    hipMemsetAsync(hist, 0, NCELL * sizeof(int), stream);
    prep_all<<<193, 256, 0, stream>>>(x, W0, W1, W2, xq, bId, hist, Wc0, Wc1, Wc2);
    prefix4096<<<1, 1024, 0, stream>>>(hist, work);
    scatter_pts<<<32, 256, 0, stream>>>(xq, bId, work, srt);
    knn_kernel<<<NPTS / 4, 256, 0, stream>>>(srt, idx);

    gemm0_kernel<<<NPTS, 128, 0, stream>>>(x, Wc0, bufA);
    maxrelu_kernel<64><<<NPTS / 16, 256, 0, stream>>>(bufA, idx, b0, bufB);

    gemm_nt<<<dim3(64, 4), 256, 0, stream>>>(bufB, Wc1, bufA, 64, 256);
    maxrelu_kernel<128><<<NPTS / 8, 256, 0, stream>>>(bufA, idx, b1, bufB);

    gemm_nt<<<dim3(64, 8), 256, 0, stream>>>(bufB, Wc2, bufA, 128, 512);
    maxrelu_kernel<256><<<NPTS / 4, 256, 0, stream>>>(bufA, idx, b2, out);
}

// Round 11
// 123.419 us; speedup vs baseline: 1.3224x; 1.1233x over previous
//
#include <hip/hip_runtime.h>
#include <math.h>

#define NPTS 8192
#define KNN  20
#define NBLK (NPTS / 64)           // 128 sorted 64-blocks
#define NCELL 4096                 // 16^3 Morton cells
#define GLO  (-4.0f)
#define GINV (2.0f)

__device__ __forceinline__ int cellof(float v) {
    int c = (int)floorf((v - GLO) * GINV);
    return min(max(c, 0), 15);
}
__device__ __forceinline__ int spread4(int b) {
    return (b & 1) | ((b & 2) << 2) | ((b & 4) << 4) | ((b & 8) << 6);
}

// 64-lane bitonic sort, ascending by lane. Keys d, payload ji.
__device__ __forceinline__ void bitonic64(float& d, int& ji, int lane) {
#pragma unroll
    for (int k = 2; k <= 64; k <<= 1) {
#pragma unroll
        for (int j = k >> 1; j > 0; j >>= 1) {
            const float od = __shfl_xor(d, j);
            const int   oi = __shfl_xor(ji, j);
            const bool up      = ((lane & k) == 0);
            const bool lower   = ((lane & j) == 0);
            const bool takeMin = (up == lower);
            const bool sw = takeMin ? (od < d) : (od > d);
            d  = sw ? od : d;
            ji = sw ? oi : ji;
        }
    }
}

__device__ __forceinline__ void bitonic_clean64(float& d, int& ji, int lane) {
#pragma unroll
    for (int j = 32; j > 0; j >>= 1) {
        const float od = __shfl_xor(d, j);
        const int   oi = __shfl_xor(ji, j);
        const bool lower = ((lane & j) == 0);
        const bool sw = lower ? (od < d) : (od > d);
        d  = sw ? od : d;
        ji = sw ? oi : ji;
    }
}

// merge LDS hit-pool (cnt entries) into the resident sorted-64 list (ld,lj)
__device__ __forceinline__ void compact(float& ld, int& lj,
                                        const float* __restrict__ sd,
                                        const int* __restrict__ sj,
                                        int cnt, int lane) {
    __builtin_amdgcn_wave_barrier();          // order pool ds_writes before reads
    float bd = (lane < cnt) ? sd[lane] : INFINITY;
    int   bj = (lane < cnt) ? sj[lane] : -1;
    bitonic64(bd, bj, lane);
    const float rd = __shfl(bd, 63 - lane);
    const int   rj = __shfl(bj, 63 - lane);
    const bool sw = rd < ld;
    float md = sw ? rd : ld;
    int   mj = sw ? rj : lj;
    bitonic_clean64(md, mj, lane);
    ld = md; lj = mj;
}

// ---------------- fused prep: xq + Morton cell id + hist + Wc0/1/2 ----------------
__device__ __forceinline__ void prep_w_elem(const float* __restrict__ W,
                                            float* __restrict__ Wc,
                                            int tid, int O, int C) {
    const int o = tid / C, k = tid % C;
    const float wa = W[o*2*C + k];
    const float wb = W[o*2*C + C + k];
    Wc[o*C + k]       = wa - wb;
    Wc[(O + o)*C + k] = wb;
}

__global__ void prep_all(const float* __restrict__ x,
                         const float* __restrict__ W0,
                         const float* __restrict__ W1,
                         const float* __restrict__ W2,
                         float4* __restrict__ xq,
                         int* __restrict__ bId,
                         int* __restrict__ hist,
                         float* __restrict__ Wc0,
                         float* __restrict__ Wc1,
                         float* __restrict__ Wc2) {
    const int bid = blockIdx.x;
    const int t = threadIdx.x;
    if (bid < 32) {
        const int i = bid * 256 + t;
        const float a = x[3*i+0], b = x[3*i+1], c = x[3*i+2];
        xq[i] = make_float4(a, b, c, 0.0f);
        const int cell = spread4(cellof(a)) | (spread4(cellof(b)) << 1)
                       | (spread4(cellof(c)) << 2);
        bId[i] = cell;
        atomicAdd(&hist[cell], 1);
    } else if (bid == 32) {
        if (t < 192) prep_w_elem(W0, Wc0, t, 64, 3);
    } else if (bid < 65) {
        prep_w_elem(W1, Wc1, (bid - 33) * 256 + t, 128, 64);
    } else {
        prep_w_elem(W2, Wc2, (bid - 65) * 256 + t, 256, 128);
    }
}

// ---------------- exclusive prefix over 4096 cells (1 block, 4/thread) ----------------
__global__ __launch_bounds__(1024) void prefix4096(const int* __restrict__ hist,
                                                   int* __restrict__ work) {
    __shared__ int s[1024];
    const int t = threadIdx.x;
    const int4 v = *reinterpret_cast<const int4*>(&hist[t * 4]);
    const int s0 = v.x, s1 = s0 + v.y, s2 = s1 + v.z, s3 = s2 + v.w;
    s[t] = s3;
    __syncthreads();
    for (int off = 1; off < 1024; off <<= 1) {
        const int u = (t >= off) ? s[t - off] : 0;
        __syncthreads();
        s[t] += u;
        __syncthreads();
    }
    const int excl = s[t] - s3;
    work[t*4+0] = excl;
    work[t*4+1] = excl + s0;
    work[t*4+2] = excl + s1;
    work[t*4+3] = excl + s2;
}

// ---------------- per-point scatter into Morton-sorted order ----------------
__global__ __launch_bounds__(256) void scatter_pts(const float4* __restrict__ xq,
                                                   const int* __restrict__ bId,
                                                   int* __restrict__ work,
                                                   float4* __restrict__ srt) {
    const int i = blockIdx.x * 256 + threadIdx.x;
    const int pos = atomicAdd(&work[bId[i]], 1);
    float4 v = xq[i];
    v.w = __int_as_float(i);
    srt[pos] = v;
}

// ---------------- per-block AABB: one wave per sorted 64-block ----------------
__global__ __launch_bounds__(256) void aabb_kernel(const float4* __restrict__ srt,
                                                   float4* __restrict__ bmin,
                                                   float4* __restrict__ bmax) {
    const int lane = threadIdx.x & 63;
    const int b = blockIdx.x * 4 + (threadIdx.x >> 6);
    const float4 v = srt[b * 64 + lane];
    float mnx = v.x, mny = v.y, mnz = v.z;
    float mxx = v.x, mxy = v.y, mxz = v.z;
#pragma unroll
    for (int off = 1; off < 64; off <<= 1) {
        mnx = fminf(mnx, __shfl_xor(mnx, off));
        mny = fminf(mny, __shfl_xor(mny, off));
        mnz = fminf(mnz, __shfl_xor(mnz, off));
        mxx = fmaxf(mxx, __shfl_xor(mxx, off));
        mxy = fmaxf(mxy, __shfl_xor(mxy, off));
        mxz = fmaxf(mxz, __shfl_xor(mxz, off));
    }
    if (lane == 0) {
        bmin[b] = make_float4(mnx, mny, mnz, 0.0f);
        bmax[b] = make_float4(mxx, mxy, mxz, 0.0f);
    }
}

// ---------------- KNN: Morton init + window pre-pass + AABB-screened scan ----------------
// 1 query/wave. (1) init top-64 from own sorted block; (2) pre-pass Morton
// window [bq-3,bq+3] tightens cm ~ true r21 uniformly (R10, kills stragglers);
// (3) each lane computes analytic lb-dist^2 to 2 block-AABBs in registers ->
// ballot -> scan only candidate blocks (~4-15) from L2-resident srt. Exact:
// any true top-21 point in block b has d < cm_screen, and lb <= d, so b is
// selected; lazy cm >= true r21 throughout. Output lanes 1..20, original ids.
__global__ __launch_bounds__(256) void knn_kernel(const float4* __restrict__ srt,
                                                  const float4* __restrict__ bmin,
                                                  const float4* __restrict__ bmax,
                                                  int* __restrict__ idx_out) {
    __shared__ float sdp[4][64];
    __shared__ int   sjp[4][64];
    const int lane = threadIdx.x & 63;
    const int wv   = threadIdx.x >> 6;
    const int s    = blockIdx.x * 4 + wv;
    float* sd = sdp[wv];
    int*   sj = sjp[wv];

    const float4 p = srt[s];
    const int qorig = __float_as_int(p.w);
    const int bq = s >> 6;

    // init: own Morton block (contains self, d=0 -> lane 0 after final sort)
    float ld, cm;
    int lj;
    {
        const float4 c = srt[(bq << 6) + lane];
        const float dx = p.x - c.x, dy = p.y - c.y, dz = p.z - c.z;
        ld = dx*dx + dy*dy + dz*dz;
        lj = __float_as_int(c.w);
        bitonic64(ld, lj, lane);
        cm = __shfl(ld, KNN);                 // 21st incl self = 20th excl
    }
    int cnt = 0;

#define APPEND(M, D, C4)                                                      \
    if (M) {                                                                  \
        const int tot = __popcll(M);                                          \
        if (cnt + tot > 64) {                                                 \
            compact(ld, lj, sd, sj, cnt, lane);                               \
            cm = __shfl(ld, KNN);                                             \
            cnt = 0;                                                          \
        }                                                                     \
        const int below = __builtin_amdgcn_mbcnt_hi(                          \
            (unsigned)((M) >> 32),                                            \
            __builtin_amdgcn_mbcnt_lo((unsigned)(M), 0));                     \
        const bool h = ((M) >> lane) & 1ull;                                  \
        if (h) { sd[cnt + below] = D; sj[cnt + below] = __float_as_int(C4.w); } \
        cnt += tot;                                                           \
    }

    // pre-pass: Morton window (direct from L2), excluding own block
    const int wlo = max(bq - 3, 0);
    const int whi = min(bq + 3, NBLK - 1);
    for (int bb = wlo; bb <= whi; ++bb) {
        if (bb == bq) continue;
        const float4 pc = srt[(bb << 6) + lane];
        const float dx = p.x - pc.x, dy = p.y - pc.y, dz = p.z - pc.z;
        const float d = dx*dx + dy*dy + dz*dz;
        const unsigned long long m = __ballot(d < cm);
        APPEND(m, d, pc)
    }
    if (cnt > 0) { compact(ld, lj, sd, sj, cnt, lane); cm = __shfl(ld, KNN); cnt = 0; }

    // AABB screen: lane handles blocks lane and lane+64
    unsigned long long mlo, mhi;
    {
        const float4 n0 = bmin[lane],      x0 = bmax[lane];
        const float4 n1 = bmin[lane + 64], x1 = bmax[lane + 64];
        float ax = fmaxf(fmaxf(n0.x - p.x, p.x - x0.x), 0.0f);
        float ay = fmaxf(fmaxf(n0.y - p.y, p.y - x0.y), 0.0f);
        float az = fmaxf(fmaxf(n0.z - p.z, p.z - x0.z), 0.0f);
        const float lb0 = ax*ax + ay*ay + az*az;
        ax = fmaxf(fmaxf(n1.x - p.x, p.x - x1.x), 0.0f);
        ay = fmaxf(fmaxf(n1.y - p.y, p.y - x1.y), 0.0f);
        az = fmaxf(fmaxf(n1.z - p.z, p.z - x1.z), 0.0f);
        const float lb1 = ax*ax + ay*ay + az*az;
        const bool h0 = (lb0 < cm) && (lane < wlo || lane > whi);
        const bool h1 = (lb1 < cm) && (lane + 64 < wlo || lane + 64 > whi);
        mlo = __ballot(h0);
        mhi = __ballot(h1);
    }

    // scan selected blocks (uniform 1KB loads from L2-resident srt)
    while (mlo | mhi) {
        int bb;
        if (mlo) { bb = __ffsll(mlo) - 1;      mlo &= (mlo - 1); }
        else     { bb = 64 + __ffsll(mhi) - 1; mhi &= (mhi - 1); }
        const float4 pc = srt[(bb << 6) + lane];
        const float dx = p.x - pc.x, dy = p.y - pc.y, dz = p.z - pc.z;
        const float d = dx*dx + dy*dy + dz*dz;
        const unsigned long long m = __ballot(d < cm);
        APPEND(m, d, pc)
    }
    if (cnt > 0) compact(ld, lj, sd, sj, cnt, lane);
#undef APPEND

    if (lane >= 1 && lane <= KNN) idx_out[qorig * KNN + lane - 1] = lj;
}

// ---------------- layer0 GEMM: K=3 special case ----------------
__global__ __launch_bounds__(128) void gemm0_kernel(const float* __restrict__ x,
                                                    const float* __restrict__ Wc,
                                                    float* __restrict__ T) {
    __shared__ float sw[384];
    const int t = threadIdx.x;
    sw[t]       = Wc[t];
    sw[t + 128] = Wc[t + 128];
    sw[t + 256] = Wc[t + 256];
    __syncthreads();
    const int n = blockIdx.x;
    const float x0 = x[3*n+0], x1 = x[3*n+1], x2 = x[3*n+2];
    T[n*128 + t] = x0*sw[3*t+0] + x1*sw[3*t+1] + x2*sw[3*t+2];
}

// ---------------- fp32 GEMM: T = H (NxK) * W^T (MxK) ----------------
#define BK 16
__global__ __launch_bounds__(256) void gemm_nt(const float* __restrict__ H,
                                               const float* __restrict__ W,
                                               float* __restrict__ T,
                                               int Kk, int Mm) {
    __shared__ float sH[BK][132];
    __shared__ float sW[BK][68];
    const int t  = threadIdx.x;
    const int rg = t & 15;
    const int cg = t >> 4;
    const int row0 = blockIdx.x * 128;
    const int col0 = blockIdx.y * 64;

    const int ar = t >> 2;
    const int ac = t & 3;

    float acc[8][4];
#pragma unroll
    for (int r = 0; r < 8; ++r)
#pragma unroll
        for (int c = 0; c < 4; ++c) acc[r][c] = 0.0f;

    for (int k0 = 0; k0 < Kk; k0 += BK) {
        const float4 ha = *reinterpret_cast<const float4*>(&H[(row0 + ar)      * Kk + k0 + ac*4]);
        const float4 hb = *reinterpret_cast<const float4*>(&H[(row0 + 64 + ar) * Kk + k0 + ac*4]);
        const float4 wa = *reinterpret_cast<const float4*>(&W[(col0 + ar)      * Kk + k0 + ac*4]);
        __syncthreads();
        sH[ac*4+0][ar]    = ha.x; sH[ac*4+1][ar]    = ha.y; sH[ac*4+2][ar]    = ha.z; sH[ac*4+3][ar]    = ha.w;
        sH[ac*4+0][64+ar] = hb.x; sH[ac*4+1][64+ar] = hb.y; sH[ac*4+2][64+ar] = hb.z; sH[ac*4+3][64+ar] = hb.w;
        sW[ac*4+0][ar]    = wa.x; sW[ac*4+1][ar]    = wa.y; sW[ac*4+2][ar]    = wa.z; sW[ac*4+3][ar]    = wa.w;
        __syncthreads();
#pragma unroll
        for (int kk = 0; kk < BK; ++kk) {
            const float4 a0 = *reinterpret_cast<const float4*>(&sH[kk][rg*4]);
            const float4 a1 = *reinterpret_cast<const float4*>(&sH[kk][64 + rg*4]);
            const float4 bv = *reinterpret_cast<const float4*>(&sW[kk][cg*4]);
            const float arr[8] = {a0.x, a0.y, a0.z, a0.w, a1.x, a1.y, a1.z, a1.w};
            const float bb[4]  = {bv.x, bv.y, bv.z, bv.w};
#pragma unroll
            for (int r = 0; r < 8; ++r)
#pragma unroll
                for (int c = 0; c < 4; ++c)
                    acc[r][c] = fmaf(arr[r], bb[c], acc[r][c]);
        }
    }
#pragma unroll
    for (int r = 0; r < 8; ++r) {
        const int row = (r < 4) ? (rg*4 + r) : (64 + rg*4 + (r - 4));
        *reinterpret_cast<float4*>(&T[(row0 + row)*Mm + col0 + cg*4]) =
            make_float4(acc[r][0], acc[r][1], acc[r][2], acc[r][3]);
    }
}

// ---------------- gather + max + bias + relu (float4 per thread) ----------------
template<int O>
__global__ __launch_bounds__(256) void maxrelu_kernel(const float* __restrict__ T,
                                                      const int* __restrict__ idx,
                                                      const float* __restrict__ bias,
                                                      float* __restrict__ out) {
    constexpr int Q   = O / 4;
    constexpr int PPB = 256 / Q;
    constexpr int M2  = 2 * O;
    const int pi = threadIdx.x / Q;
    const int oq = threadIdx.x & (Q - 1);
    const int i  = blockIdx.x * PPB + pi;
    __shared__ int sidx[PPB * KNN];
    for (int t = threadIdx.x; t < PPB * KNN; t += 256)
        sidx[t] = idx[blockIdx.x * PPB * KNN + t];
    __syncthreads();
    const int sb = pi * KNN;
    float4 m = make_float4(-INFINITY, -INFINITY, -INFINITY, -INFINITY);
#pragma unroll
    for (int k = 0; k < KNN; ++k) {
        const float4 v = *reinterpret_cast<const float4*>(&T[sidx[sb + k] * M2 + O + oq * 4]);
        m.x = fmaxf(m.x, v.x); m.y = fmaxf(m.y, v.y);
        m.z = fmaxf(m.z, v.z); m.w = fmaxf(m.w, v.w);
    }
    const float4 b = *reinterpret_cast<const float4*>(&T[i * M2 + oq * 4]);
    const float4 bv = *reinterpret_cast<const float4*>(&bias[oq * 4]);
    float4 o;
    o.x = fmaxf(b.x + bv.x + m.x, 0.0f);
    o.y = fmaxf(b.y + bv.y + m.y, 0.0f);
    o.z = fmaxf(b.z + bv.z + m.z, 0.0f);
    o.w = fmaxf(b.w + bv.w + m.w, 0.0f);
    *reinterpret_cast<float4*>(&out[i * O + oq * 4]) = o;
}

extern "C" void kernel_launch(void* const* d_in, const int* in_sizes, int n_in,
                              void* d_out, int out_size, void* d_ws, size_t ws_size,
                              hipStream_t stream) {
    const float* x  = (const float*)d_in[0];
    const float* W0 = (const float*)d_in[1];
    const float* b0 = (const float*)d_in[2];
    const float* W1 = (const float*)d_in[3];
    const float* b1 = (const float*)d_in[4];
    const float* W2 = (const float*)d_in[5];
    const float* b2 = (const float*)d_in[6];
    float* out = (float*)d_out;
    char*  ws  = (char*)d_ws;

    int*   idx  = (int*)(ws + 0);                 // 655360
    float* Wc0  = (float*)(ws + 655360);          // 1536
    float* Wc1  = (float*)(ws + 656896);          // 65536
    float* Wc2  = (float*)(ws + 722432);          // 262144
    float* bufA = (float*)(ws + 984576);          // 16 MB
    float* bufB = (float*)(ws + 17761792);        // 4 MB

    // knn-phase scratch aliases bufA (dead before gemm0 writes bufA)
    float4* xq   = (float4*)bufA;                       // 128 KB
    float4* srt  = (float4*)((char*)bufA + 131072);     // 128 KB
    int*    bId  = (int*)((char*)bufA + 262144);        // 32 KB
    int*    hist = (int*)((char*)bufA + 294912);        // 16 KB
    int*    work = (int*)((char*)bufA + 311296);        // 16 KB
    float4* bmin = (float4*)((char*)bufA + 327680);     // 2 KB
    float4* bmax = (float4*)((char*)bufA + 329728);     // 2 KB

    hipMemsetAsync(hist, 0, NCELL * sizeof(int), stream);
    prep_all<<<193, 256, 0, stream>>>(x, W0, W1, W2, xq, bId, hist, Wc0, Wc1, Wc2);
    prefix4096<<<1, 1024, 0, stream>>>(hist, work);
    scatter_pts<<<32, 256, 0, stream>>>(xq, bId, work, srt);
    aabb_kernel<<<NBLK / 4, 256, 0, stream>>>(srt, bmin, bmax);
    knn_kernel<<<NPTS / 4, 256, 0, stream>>>(srt, bmin, bmax, idx);

    gemm0_kernel<<<NPTS, 128, 0, stream>>>(x, Wc0, bufA);
    maxrelu_kernel<64><<<NPTS / 16, 256, 0, stream>>>(bufA, idx, b0, bufB);

    gemm_nt<<<dim3(64, 4), 256, 0, stream>>>(bufB, Wc1, bufA, 64, 256);
    maxrelu_kernel<128><<<NPTS / 8, 256, 0, stream>>>(bufA, idx, b1, bufB);

    gemm_nt<<<dim3(64, 8), 256, 0, stream>>>(bufB, Wc2, bufA, 128, 512);
    maxrelu_kernel<256><<<NPTS / 4, 256, 0, stream>>>(bufA, idx, b2, out);
}

// Round 12
// 121.856 us; speedup vs baseline: 1.3394x; 1.0128x over previous
//
#include <hip/hip_runtime.h>
#include <math.h>

#define NPTS 8192
#define KNN  20
#define NBLK (NPTS / 64)           // 128 sorted 64-blocks
#define NCELL 4096                 // 16^3 Morton cells
#define GLO  (-4.0f)
#define GINV (2.0f)

__device__ __forceinline__ int cellof(float v) {
    int c = (int)floorf((v - GLO) * GINV);
    return min(max(c, 0), 15);
}
__device__ __forceinline__ int spread4(int b) {
    return (b & 1) | ((b & 2) << 2) | ((b & 4) << 4) | ((b & 8) << 6);
}

// 64-lane bitonic sort, ascending by lane. Keys d, payload ji.
__device__ __forceinline__ void bitonic64(float& d, int& ji, int lane) {
#pragma unroll
    for (int k = 2; k <= 64; k <<= 1) {
#pragma unroll
        for (int j = k >> 1; j > 0; j >>= 1) {
            const float od = __shfl_xor(d, j);
            const int   oi = __shfl_xor(ji, j);
            const bool up      = ((lane & k) == 0);
            const bool lower   = ((lane & j) == 0);
            const bool takeMin = (up == lower);
            const bool sw = takeMin ? (od < d) : (od > d);
            d  = sw ? od : d;
            ji = sw ? oi : ji;
        }
    }
}

__device__ __forceinline__ void bitonic_clean64(float& d, int& ji, int lane) {
#pragma unroll
    for (int j = 32; j > 0; j >>= 1) {
        const float od = __shfl_xor(d, j);
        const int   oi = __shfl_xor(ji, j);
        const bool lower = ((lane & j) == 0);
        const bool sw = lower ? (od < d) : (od > d);
        d  = sw ? od : d;
        ji = sw ? oi : ji;
    }
}

// merge LDS hit-pool (cnt entries) into the resident sorted-64 list (ld,lj)
__device__ __forceinline__ void compact(float& ld, int& lj,
                                        const float* __restrict__ sd,
                                        const int* __restrict__ sj,
                                        int cnt, int lane) {
    __builtin_amdgcn_wave_barrier();          // order pool ds_writes before reads
    float bd = (lane < cnt) ? sd[lane] : INFINITY;
    int   bj = (lane < cnt) ? sj[lane] : -1;
    bitonic64(bd, bj, lane);
    const float rd = __shfl(bd, 63 - lane);
    const int   rj = __shfl(bj, 63 - lane);
    const bool sw = rd < ld;
    float md = sw ? rd : ld;
    int   mj = sw ? rj : lj;
    bitonic_clean64(md, mj, lane);
    ld = md; lj = mj;
}

// ---------------- fused prep: xq + Morton cell id + per-block hist + Wc0/1/2 ----------------
// Blocks 0..31: 256 points each; LDS histogram (no global atomics, no memset
// needed -- every hist_part entry is written). Blocks 32+: weight restructure.
__device__ __forceinline__ void prep_w_elem(const float* __restrict__ W,
                                            float* __restrict__ Wc,
                                            int tid, int O, int C) {
    const int o = tid / C, k = tid % C;
    const float wa = W[o*2*C + k];
    const float wb = W[o*2*C + C + k];
    Wc[o*C + k]       = wa - wb;
    Wc[(O + o)*C + k] = wb;
}

__global__ void prep_all(const float* __restrict__ x,
                         const float* __restrict__ W0,
                         const float* __restrict__ W1,
                         const float* __restrict__ W2,
                         float4* __restrict__ xq,
                         int* __restrict__ bId,
                         int* __restrict__ hist_part,
                         float* __restrict__ Wc0,
                         float* __restrict__ Wc1,
                         float* __restrict__ Wc2) {
    __shared__ int lh[NCELL];
    const int bid = blockIdx.x;
    const int t = threadIdx.x;
    if (bid < 32) {
        for (int u = t; u < NCELL; u += 256) lh[u] = 0;
        __syncthreads();
        const int i = bid * 256 + t;
        const float a = x[3*i+0], b = x[3*i+1], c = x[3*i+2];
        xq[i] = make_float4(a, b, c, 0.0f);
        const int cell = spread4(cellof(a)) | (spread4(cellof(b)) << 1)
                       | (spread4(cellof(c)) << 2);
        bId[i] = cell;
        atomicAdd(&lh[cell], 1);
        __syncthreads();
        for (int u = t; u < NCELL; u += 256) hist_part[bid * NCELL + u] = lh[u];
    } else if (bid == 32) {
        if (t < 192) prep_w_elem(W0, Wc0, t, 64, 3);
    } else if (bid < 65) {
        prep_w_elem(W1, Wc1, (bid - 33) * 256 + t, 128, 64);
    } else {
        prep_w_elem(W2, Wc2, (bid - 65) * 256 + t, 256, 128);
    }
}

// ---------------- sum partials + exclusive prefix over 4096 cells ----------------
__global__ __launch_bounds__(1024) void prefix4096(const int* __restrict__ hist_part,
                                                   int* __restrict__ work) {
    __shared__ int s[1024];
    const int t = threadIdx.x;
    int4 v = make_int4(0, 0, 0, 0);
    for (int p = 0; p < 32; ++p) {
        const int4 h = *reinterpret_cast<const int4*>(&hist_part[p * NCELL + t * 4]);
        v.x += h.x; v.y += h.y; v.z += h.z; v.w += h.w;
    }
    const int s0 = v.x, s1 = s0 + v.y, s2 = s1 + v.z, s3 = s2 + v.w;
    s[t] = s3;
    __syncthreads();
    for (int off = 1; off < 1024; off <<= 1) {
        const int u = (t >= off) ? s[t - off] : 0;
        __syncthreads();
        s[t] += u;
        __syncthreads();
    }
    const int excl = s[t] - s3;
    work[t*4+0] = excl;
    work[t*4+1] = excl + s0;
    work[t*4+2] = excl + s1;
    work[t*4+3] = excl + s2;
}

// ---------------- per-point scatter into Morton-sorted order ----------------
__global__ __launch_bounds__(256) void scatter_pts(const float4* __restrict__ xq,
                                                   const int* __restrict__ bId,
                                                   int* __restrict__ work,
                                                   float4* __restrict__ srt) {
    const int i = blockIdx.x * 256 + threadIdx.x;
    const int pos = atomicAdd(&work[bId[i]], 1);
    float4 v = xq[i];
    v.w = __int_as_float(i);
    srt[pos] = v;
}

// ---------------- per-block AABB: one wave per sorted 64-block ----------------
__global__ __launch_bounds__(256) void aabb_kernel(const float4* __restrict__ srt,
                                                   float4* __restrict__ bmin,
                                                   float4* __restrict__ bmax) {
    const int lane = threadIdx.x & 63;
    const int b = blockIdx.x * 4 + (threadIdx.x >> 6);
    const float4 v = srt[b * 64 + lane];
    float mnx = v.x, mny = v.y, mnz = v.z;
    float mxx = v.x, mxy = v.y, mxz = v.z;
#pragma unroll
    for (int off = 1; off < 64; off <<= 1) {
        mnx = fminf(mnx, __shfl_xor(mnx, off));
        mny = fminf(mny, __shfl_xor(mny, off));
        mnz = fminf(mnz, __shfl_xor(mnz, off));
        mxx = fmaxf(mxx, __shfl_xor(mxx, off));
        mxy = fmaxf(mxy, __shfl_xor(mxy, off));
        mxz = fmaxf(mxz, __shfl_xor(mxz, off));
    }
    if (lane == 0) {
        bmin[b] = make_float4(mnx, mny, mnz, 0.0f);
        bmax[b] = make_float4(mxx, mxy, mxz, 0.0f);
    }
}

// ---------------- KNN: Morton init + window pre-pass + AABB-screened scan ----------------
__global__ __launch_bounds__(256) void knn_kernel(const float4* __restrict__ srt,
                                                  const float4* __restrict__ bmin,
                                                  const float4* __restrict__ bmax,
                                                  int* __restrict__ idx_out) {
    __shared__ float sdp[4][64];
    __shared__ int   sjp[4][64];
    const int lane = threadIdx.x & 63;
    const int wv   = threadIdx.x >> 6;
    const int s    = blockIdx.x * 4 + wv;
    float* sd = sdp[wv];
    int*   sj = sjp[wv];

    const float4 p = srt[s];
    const int qorig = __float_as_int(p.w);
    const int bq = s >> 6;

    // init: own Morton block (contains self, d=0 -> lane 0 after final sort)
    float ld, cm;
    int lj;
    {
        const float4 c = srt[(bq << 6) + lane];
        const float dx = p.x - c.x, dy = p.y - c.y, dz = p.z - c.z;
        ld = dx*dx + dy*dy + dz*dz;
        lj = __float_as_int(c.w);
        bitonic64(ld, lj, lane);
        cm = __shfl(ld, KNN);                 // 21st incl self = 20th excl
    }
    int cnt = 0;

#define APPEND(M, D, C4)                                                      \
    if (M) {                                                                  \
        const int tot = __popcll(M);                                          \
        if (cnt + tot > 64) {                                                 \
            compact(ld, lj, sd, sj, cnt, lane);                               \
            cm = __shfl(ld, KNN);                                             \
            cnt = 0;                                                          \
        }                                                                     \
        const int below = __builtin_amdgcn_mbcnt_hi(                          \
            (unsigned)((M) >> 32),                                            \
            __builtin_amdgcn_mbcnt_lo((unsigned)(M), 0));                     \
        const bool h = ((M) >> lane) & 1ull;                                  \
        if (h) { sd[cnt + below] = D; sj[cnt + below] = __float_as_int(C4.w); } \
        cnt += tot;                                                           \
    }

    // pre-pass: Morton window (direct from L2), excluding own block
    const int wlo = max(bq - 3, 0);
    const int whi = min(bq + 3, NBLK - 1);
    for (int bb = wlo; bb <= whi; ++bb) {
        if (bb == bq) continue;
        const float4 pc = srt[(bb << 6) + lane];
        const float dx = p.x - pc.x, dy = p.y - pc.y, dz = p.z - pc.z;
        const float d = dx*dx + dy*dy + dz*dz;
        const unsigned long long m = __ballot(d < cm);
        APPEND(m, d, pc)
    }
    if (cnt > 0) { compact(ld, lj, sd, sj, cnt, lane); cm = __shfl(ld, KNN); cnt = 0; }

    // AABB screen: lane handles blocks lane and lane+64
    unsigned long long mlo, mhi;
    {
        const float4 n0 = bmin[lane],      x0 = bmax[lane];
        const float4 n1 = bmin[lane + 64], x1 = bmax[lane + 64];
        float ax = fmaxf(fmaxf(n0.x - p.x, p.x - x0.x), 0.0f);
        float ay = fmaxf(fmaxf(n0.y - p.y, p.y - x0.y), 0.0f);
        float az = fmaxf(fmaxf(n0.z - p.z, p.z - x0.z), 0.0f);
        const float lb0 = ax*ax + ay*ay + az*az;
        ax = fmaxf(fmaxf(n1.x - p.x, p.x - x1.x), 0.0f);
        ay = fmaxf(fmaxf(n1.y - p.y, p.y - x1.y), 0.0f);
        az = fmaxf(fmaxf(n1.z - p.z, p.z - x1.z), 0.0f);
        const float lb1 = ax*ax + ay*ay + az*az;
        const bool h0 = (lb0 < cm) && (lane < wlo || lane > whi);
        const bool h1 = (lb1 < cm) && (lane + 64 < wlo || lane + 64 > whi);
        mlo = __ballot(h0);
        mhi = __ballot(h1);
    }

    // scan selected blocks (uniform 1KB loads from L2-resident srt)
    while (mlo | mhi) {
        int bb;
        if (mlo) { bb = __ffsll(mlo) - 1;      mlo &= (mlo - 1); }
        else     { bb = 64 + __ffsll(mhi) - 1; mhi &= (mhi - 1); }
        const float4 pc = srt[(bb << 6) + lane];
        const float dx = p.x - pc.x, dy = p.y - pc.y, dz = p.z - pc.z;
        const float d = dx*dx + dy*dy + dz*dz;
        const unsigned long long m = __ballot(d < cm);
        APPEND(m, d, pc)
    }
    if (cnt > 0) compact(ld, lj, sd, sj, cnt, lane);
#undef APPEND

    if (lane >= 1 && lane <= KNN) idx_out[qorig * KNN + lane - 1] = lj;
}

// ---------------- layer0 GEMM: K=3 special case ----------------
__global__ __launch_bounds__(128) void gemm0_kernel(const float* __restrict__ x,
                                                    const float* __restrict__ Wc,
                                                    float* __restrict__ T) {
    __shared__ float sw[384];
    const int t = threadIdx.x;
    sw[t]       = Wc[t];
    sw[t + 128] = Wc[t + 128];
    sw[t + 256] = Wc[t + 256];
    __syncthreads();
    const int n = blockIdx.x;
    const float x0 = x[3*n+0], x1 = x[3*n+1], x2 = x[3*n+2];
    T[n*128 + t] = x0*sw[3*t+0] + x1*sw[3*t+1] + x2*sw[3*t+2];
}

// ---------------- fp32 GEMM: T = H (NxK) * W^T (MxK) ----------------
#define BK 16
__global__ __launch_bounds__(256) void gemm_nt(const float* __restrict__ H,
                                               const float* __restrict__ W,
                                               float* __restrict__ T,
                                               int Kk, int Mm) {
    __shared__ float sH[BK][132];
    __shared__ float sW[BK][68];
    const int t  = threadIdx.x;
    const int rg = t & 15;
    const int cg = t >> 4;
    const int row0 = blockIdx.x * 128;
    const int col0 = blockIdx.y * 64;

    const int ar = t >> 2;
    const int ac = t & 3;

    float acc[8][4];
#pragma unroll
    for (int r = 0; r < 8; ++r)
#pragma unroll
        for (int c = 0; c < 4; ++c) acc[r][c] = 0.0f;

    for (int k0 = 0; k0 < Kk; k0 += BK) {
        const float4 ha = *reinterpret_cast<const float4*>(&H[(row0 + ar)      * Kk + k0 + ac*4]);
        const float4 hb = *reinterpret_cast<const float4*>(&H[(row0 + 64 + ar) * Kk + k0 + ac*4]);
        const float4 wa = *reinterpret_cast<const float4*>(&W[(col0 + ar)      * Kk + k0 + ac*4]);
        __syncthreads();
        sH[ac*4+0][ar]    = ha.x; sH[ac*4+1][ar]    = ha.y; sH[ac*4+2][ar]    = ha.z; sH[ac*4+3][ar]    = ha.w;
        sH[ac*4+0][64+ar] = hb.x; sH[ac*4+1][64+ar] = hb.y; sH[ac*4+2][64+ar] = hb.z; sH[ac*4+3][64+ar] = hb.w;
        sW[ac*4+0][ar]    = wa.x; sW[ac*4+1][ar]    = wa.y; sW[ac*4+2][ar]    = wa.z; sW[ac*4+3][ar]    = wa.w;
        __syncthreads();
#pragma unroll
        for (int kk = 0; kk < BK; ++kk) {
            const float4 a0 = *reinterpret_cast<const float4*>(&sH[kk][rg*4]);
            const float4 a1 = *reinterpret_cast<const float4*>(&sH[kk][64 + rg*4]);
            const float4 bv = *reinterpret_cast<const float4*>(&sW[kk][cg*4]);
            const float arr[8] = {a0.x, a0.y, a0.z, a0.w, a1.x, a1.y, a1.z, a1.w};
            const float bb[4]  = {bv.x, bv.y, bv.z, bv.w};
#pragma unroll
            for (int r = 0; r < 8; ++r)
#pragma unroll
                for (int c = 0; c < 4; ++c)
                    acc[r][c] = fmaf(arr[r], bb[c], acc[r][c]);
        }
    }
#pragma unroll
    for (int r = 0; r < 8; ++r) {
        const int row = (r < 4) ? (rg*4 + r) : (64 + rg*4 + (r - 4));
        *reinterpret_cast<float4*>(&T[(row0 + row)*Mm + col0 + cg*4]) =
            make_float4(acc[r][0], acc[r][1], acc[r][2], acc[r][3]);
    }
}

// ---------------- gather + max + bias + relu (float4 per thread) ----------------
template<int O>
__global__ __launch_bounds__(256) void maxrelu_kernel(const float* __restrict__ T,
                                                      const int* __restrict__ idx,
                                                      const float* __restrict__ bias,
                                                      float* __restrict__ out) {
    constexpr int Q   = O / 4;
    constexpr int PPB = 256 / Q;
    constexpr int M2  = 2 * O;
    const int pi = threadIdx.x / Q;
    const int oq = threadIdx.x & (Q - 1);
    const int i  = blockIdx.x * PPB + pi;
    __shared__ int sidx[PPB * KNN];
    for (int t = threadIdx.x; t < PPB * KNN; t += 256)
        sidx[t] = idx[blockIdx.x * PPB * KNN + t];
    __syncthreads();
    const int sb = pi * KNN;
    float4 m = make_float4(-INFINITY, -INFINITY, -INFINITY, -INFINITY);
#pragma unroll
    for (int k = 0; k < KNN; ++k) {
        const float4 v = *reinterpret_cast<const float4*>(&T[sidx[sb + k] * M2 + O + oq * 4]);
        m.x = fmaxf(m.x, v.x); m.y = fmaxf(m.y, v.y);
        m.z = fmaxf(m.z, v.z); m.w = fmaxf(m.w, v.w);
    }
    const float4 b = *reinterpret_cast<const float4*>(&T[i * M2 + oq * 4]);
    const float4 bv = *reinterpret_cast<const float4*>(&bias[oq * 4]);
    float4 o;
    o.x = fmaxf(b.x + bv.x + m.x, 0.0f);
    o.y = fmaxf(b.y + bv.y + m.y, 0.0f);
    o.z = fmaxf(b.z + bv.z + m.z, 0.0f);
    o.w = fmaxf(b.w + bv.w + m.w, 0.0f);
    *reinterpret_cast<float4*>(&out[i * O + oq * 4]) = o;
}

extern "C" void kernel_launch(void* const* d_in, const int* in_sizes, int n_in,
                              void* d_out, int out_size, void* d_ws, size_t ws_size,
                              hipStream_t stream) {
    const float* x  = (const float*)d_in[0];
    const float* W0 = (const float*)d_in[1];
    const float* b0 = (const float*)d_in[2];
    const float* W1 = (const float*)d_in[3];
    const float* b1 = (const float*)d_in[4];
    const float* W2 = (const float*)d_in[5];
    const float* b2 = (const float*)d_in[6];
    float* out = (float*)d_out;
    char*  ws  = (char*)d_ws;

    int*   idx  = (int*)(ws + 0);                 // 655360
    float* Wc0  = (float*)(ws + 655360);          // 1536
    float* Wc1  = (float*)(ws + 656896);          // 65536
    float* Wc2  = (float*)(ws + 722432);          // 262144
    float* bufA = (float*)(ws + 984576);          // 16 MB
    float* bufB = (float*)(ws + 17761792);        // 4 MB

    // knn-phase scratch aliases bufA (dead before gemm0 writes bufA)
    float4* xq        = (float4*)bufA;                    // 128 KB @ 0
    float4* srt       = (float4*)((char*)bufA + 131072);  // 128 KB
    int*    bId       = (int*)((char*)bufA + 262144);     // 32 KB
    int*    hist_part = (int*)((char*)bufA + 294912);     // 32*16 KB = 512 KB
    int*    work      = (int*)((char*)bufA + 819200);     // 16 KB
    float4* bmin      = (float4*)((char*)bufA + 835584);  // 2 KB
    float4* bmax      = (float4*)((char*)bufA + 837632);  // 2 KB

    prep_all<<<193, 256, 0, stream>>>(x, W0, W1, W2, xq, bId, hist_part, Wc0, Wc1, Wc2);
    prefix4096<<<1, 1024, 0, stream>>>(hist_part, work);
    scatter_pts<<<32, 256, 0, stream>>>(xq, bId, work, srt);
    aabb_kernel<<<NBLK / 4, 256, 0, stream>>>(srt, bmin, bmax);
    knn_kernel<<<NPTS / 4, 256, 0, stream>>>(srt, bmin, bmax, idx);

    gemm0_kernel<<<NPTS, 128, 0, stream>>>(x, Wc0, bufA);
    maxrelu_kernel<64><<<NPTS / 16, 256, 0, stream>>>(bufA, idx, b0, bufB);

    gemm_nt<<<dim3(64, 4), 256, 0, stream>>>(bufB, Wc1, bufA, 64, 256);
    maxrelu_kernel<128><<<NPTS / 8, 256, 0, stream>>>(bufA, idx, b1, bufB);

    gemm_nt<<<dim3(64, 8), 256, 0, stream>>>(bufB, Wc2, bufA, 128, 512);
    maxrelu_kernel<256><<<NPTS / 4, 256, 0, stream>>>(bufA, idx, b2, out);
}

// Round 13
// 109.119 us; speedup vs baseline: 1.4957x; 1.1167x over previous
//
#include <hip/hip_runtime.h>
#include <hip/hip_bf16.h>
#include <math.h>

#define NPTS 8192
#define KNN  20
#define NBLK (NPTS / 64)           // 128 sorted 64-blocks
#define NCELL 4096                 // 16^3 Morton cells
#define GLO  (-4.0f)
#define GINV (2.0f)

typedef __attribute__((ext_vector_type(8))) short short8v;
typedef __attribute__((ext_vector_type(4))) float f32x4v;

__device__ __forceinline__ int cellof(float v) {
    int c = (int)floorf((v - GLO) * GINV);
    return min(max(c, 0), 15);
}
__device__ __forceinline__ int spread4(int b) {
    return (b & 1) | ((b & 2) << 2) | ((b & 4) << 4) | ((b & 8) << 6);
}

// 64-lane bitonic sort, ascending by lane. Keys d, payload ji.
__device__ __forceinline__ void bitonic64(float& d, int& ji, int lane) {
#pragma unroll
    for (int k = 2; k <= 64; k <<= 1) {
#pragma unroll
        for (int j = k >> 1; j > 0; j >>= 1) {
            const float od = __shfl_xor(d, j);
            const int   oi = __shfl_xor(ji, j);
            const bool up      = ((lane & k) == 0);
            const bool lower   = ((lane & j) == 0);
            const bool takeMin = (up == lower);
            const bool sw = takeMin ? (od < d) : (od > d);
            d  = sw ? od : d;
            ji = sw ? oi : ji;
        }
    }
}

__device__ __forceinline__ void bitonic_clean64(float& d, int& ji, int lane) {
#pragma unroll
    for (int j = 32; j > 0; j >>= 1) {
        const float od = __shfl_xor(d, j);
        const int   oi = __shfl_xor(ji, j);
        const bool lower = ((lane & j) == 0);
        const bool sw = lower ? (od < d) : (od > d);
        d  = sw ? od : d;
        ji = sw ? oi : ji;
    }
}

// merge LDS hit-pool (cnt entries) into the resident sorted-64 list (ld,lj)
__device__ __forceinline__ void compact(float& ld, int& lj,
                                        const float* __restrict__ sd,
                                        const int* __restrict__ sj,
                                        int cnt, int lane) {
    __builtin_amdgcn_wave_barrier();          // order pool ds_writes before reads
    float bd = (lane < cnt) ? sd[lane] : INFINITY;
    int   bj = (lane < cnt) ? sj[lane] : -1;
    bitonic64(bd, bj, lane);
    const float rd = __shfl(bd, 63 - lane);
    const int   rj = __shfl(bj, 63 - lane);
    const bool sw = rd < ld;
    float md = sw ? rd : ld;
    int   mj = sw ? rj : lj;
    bitonic_clean64(md, mj, lane);
    ld = md; lj = mj;
}

// ---------------- fused prep: xq + Morton cell id + per-block hist + Wc ----------------
// Blocks 0..7: 1024 points each (LDS histogram -> hist_part, no atomics on
// global, no memset). Block 8: Wc0 fp32. Blocks 9..40: Wc1 bf16. 41..168: Wc2 bf16.
__device__ __forceinline__ void prep_w_elem(const float* __restrict__ W,
                                            float* __restrict__ Wc,
                                            int tid, int O, int C) {
    const int o = tid / C, k = tid % C;
    const float wa = W[o*2*C + k];
    const float wb = W[o*2*C + C + k];
    Wc[o*C + k]       = wa - wb;
    Wc[(O + o)*C + k] = wb;
}

__device__ __forceinline__ void prep_w_elem_b(const float* __restrict__ W,
                                              __hip_bfloat16* __restrict__ Wc,
                                              int tid, int O, int C) {
    const int o = tid / C, k = tid % C;
    const float wa = W[o*2*C + k];
    const float wb = W[o*2*C + C + k];
    Wc[o*C + k]       = __float2bfloat16(wa - wb);
    Wc[(O + o)*C + k] = __float2bfloat16(wb);
}

__global__ void prep_all(const float* __restrict__ x,
                         const float* __restrict__ W0,
                         const float* __restrict__ W1,
                         const float* __restrict__ W2,
                         float4* __restrict__ xq,
                         int* __restrict__ bId,
                         int* __restrict__ hist_part,
                         float* __restrict__ Wc0,
                         __hip_bfloat16* __restrict__ Wc1,
                         __hip_bfloat16* __restrict__ Wc2) {
    __shared__ int lh[NCELL];
    const int bid = blockIdx.x;
    const int t = threadIdx.x;
    if (bid < 8) {
        for (int u = t; u < NCELL; u += 256) lh[u] = 0;
        __syncthreads();
#pragma unroll
        for (int u = 0; u < 4; ++u) {
            const int i = bid * 1024 + u * 256 + t;
            const float a = x[3*i+0], b = x[3*i+1], c = x[3*i+2];
            xq[i] = make_float4(a, b, c, 0.0f);
            const int cell = spread4(cellof(a)) | (spread4(cellof(b)) << 1)
                           | (spread4(cellof(c)) << 2);
            bId[i] = cell;
            atomicAdd(&lh[cell], 1);
        }
        __syncthreads();
        for (int u = t; u < NCELL; u += 256) hist_part[bid * NCELL + u] = lh[u];
    } else if (bid == 8) {
        if (t < 192) prep_w_elem(W0, Wc0, t, 64, 3);
    } else if (bid < 41) {
        prep_w_elem_b(W1, Wc1, (bid - 9) * 256 + t, 128, 64);
    } else {
        prep_w_elem_b(W2, Wc2, (bid - 41) * 256 + t, 256, 128);
    }
}

// ---------------- sum 8 partials + exclusive prefix over 4096 cells ----------------
__global__ __launch_bounds__(1024) void prefix4096(const int* __restrict__ hist_part,
                                                   int* __restrict__ work) {
    __shared__ int s[1024];
    const int t = threadIdx.x;
    int4 v = make_int4(0, 0, 0, 0);
#pragma unroll
    for (int p = 0; p < 8; ++p) {
        const int4 h = *reinterpret_cast<const int4*>(&hist_part[p * NCELL + t * 4]);
        v.x += h.x; v.y += h.y; v.z += h.z; v.w += h.w;
    }
    const int s0 = v.x, s1 = s0 + v.y, s2 = s1 + v.z, s3 = s2 + v.w;
    s[t] = s3;
    __syncthreads();
    for (int off = 1; off < 1024; off <<= 1) {
        const int u = (t >= off) ? s[t - off] : 0;
        __syncthreads();
        s[t] += u;
        __syncthreads();
    }
    const int excl = s[t] - s3;
    work[t*4+0] = excl;
    work[t*4+1] = excl + s0;
    work[t*4+2] = excl + s1;
    work[t*4+3] = excl + s2;
}

// ---------------- per-point scatter into Morton-sorted order ----------------
__global__ __launch_bounds__(256) void scatter_pts(const float4* __restrict__ xq,
                                                   const int* __restrict__ bId,
                                                   int* __restrict__ work,
                                                   float4* __restrict__ srt) {
    const int i = blockIdx.x * 256 + threadIdx.x;
    const int pos = atomicAdd(&work[bId[i]], 1);
    float4 v = xq[i];
    v.w = __int_as_float(i);
    srt[pos] = v;
}

// ---------------- per-block AABB: one wave per sorted 64-block ----------------
__global__ __launch_bounds__(256) void aabb_kernel(const float4* __restrict__ srt,
                                                   float4* __restrict__ bmin,
                                                   float4* __restrict__ bmax) {
    const int lane = threadIdx.x & 63;
    const int b = blockIdx.x * 4 + (threadIdx.x >> 6);
    const float4 v = srt[b * 64 + lane];
    float mnx = v.x, mny = v.y, mnz = v.z;
    float mxx = v.x, mxy = v.y, mxz = v.z;
#pragma unroll
    for (int off = 1; off < 64; off <<= 1) {
        mnx = fminf(mnx, __shfl_xor(mnx, off));
        mny = fminf(mny, __shfl_xor(mny, off));
        mnz = fminf(mnz, __shfl_xor(mnz, off));
        mxx = fmaxf(mxx, __shfl_xor(mxx, off));
        mxy = fmaxf(mxy, __shfl_xor(mxy, off));
        mxz = fmaxf(mxz, __shfl_xor(mxz, off));
    }
    if (lane == 0) {
        bmin[b] = make_float4(mnx, mny, mnz, 0.0f);
        bmax[b] = make_float4(mxx, mxy, mxz, 0.0f);
    }
}

// ---------------- KNN: Morton init + window pre-pass + AABB-screened scan ----------------
__global__ __launch_bounds__(256) void knn_kernel(const float4* __restrict__ srt,
                                                  const float4* __restrict__ bmin,
                                                  const float4* __restrict__ bmax,
                                                  int* __restrict__ idx_out) {
    __shared__ float sdp[4][64];
    __shared__ int   sjp[4][64];
    const int lane = threadIdx.x & 63;
    const int wv   = threadIdx.x >> 6;
    const int s    = blockIdx.x * 4 + wv;
    float* sd = sdp[wv];
    int*   sj = sjp[wv];

    const float4 p = srt[s];
    const int qorig = __float_as_int(p.w);
    const int bq = s >> 6;

    // init: own Morton block (contains self, d=0 -> lane 0 after final sort)
    float ld, cm;
    int lj;
    {
        const float4 c = srt[(bq << 6) + lane];
        const float dx = p.x - c.x, dy = p.y - c.y, dz = p.z - c.z;
        ld = dx*dx + dy*dy + dz*dz;
        lj = __float_as_int(c.w);
        bitonic64(ld, lj, lane);
        cm = __shfl(ld, KNN);                 // 21st incl self = 20th excl
    }
    int cnt = 0;

#define APPEND(M, D, C4)                                                      \
    if (M) {                                                                  \
        const int tot = __popcll(M);                                          \
        if (cnt + tot > 64) {                                                 \
            compact(ld, lj, sd, sj, cnt, lane);                               \
            cm = __shfl(ld, KNN);                                             \
            cnt = 0;                                                          \
        }                                                                     \
        const int below = __builtin_amdgcn_mbcnt_hi(                          \
            (unsigned)((M) >> 32),                                            \
            __builtin_amdgcn_mbcnt_lo((unsigned)(M), 0));                     \
        const bool h = ((M) >> lane) & 1ull;                                  \
        if (h) { sd[cnt + below] = D; sj[cnt + below] = __float_as_int(C4.w); } \
        cnt += tot;                                                           \
    }

    // pre-pass: Morton window (direct from L2), excluding own block
    const int wlo = max(bq - 3, 0);
    const int whi = min(bq + 3, NBLK - 1);
    for (int bb = wlo; bb <= whi; ++bb) {
        if (bb == bq) continue;
        const float4 pc = srt[(bb << 6) + lane];
        const float dx = p.x - pc.x, dy = p.y - pc.y, dz = p.z - pc.z;
        const float d = dx*dx + dy*dy + dz*dz;
        const unsigned long long m = __ballot(d < cm);
        APPEND(m, d, pc)
    }
    if (cnt > 0) { compact(ld, lj, sd, sj, cnt, lane); cm = __shfl(ld, KNN); cnt = 0; }

    // AABB screen: lane handles blocks lane and lane+64
    unsigned long long mlo, mhi;
    {
        const float4 n0 = bmin[lane],      x0 = bmax[lane];
        const float4 n1 = bmin[lane + 64], x1 = bmax[lane + 64];
        float ax = fmaxf(fmaxf(n0.x - p.x, p.x - x0.x), 0.0f);
        float ay = fmaxf(fmaxf(n0.y - p.y, p.y - x0.y), 0.0f);
        float az = fmaxf(fmaxf(n0.z - p.z, p.z - x0.z), 0.0f);
        const float lb0 = ax*ax + ay*ay + az*az;
        ax = fmaxf(fmaxf(n1.x - p.x, p.x - x1.x), 0.0f);
        ay = fmaxf(fmaxf(n1.y - p.y, p.y - x1.y), 0.0f);
        az = fmaxf(fmaxf(n1.z - p.z, p.z - x1.z), 0.0f);
        const float lb1 = ax*ax + ay*ay + az*az;
        const bool h0 = (lb0 < cm) && (lane < wlo || lane > whi);
        const bool h1 = (lb1 < cm) && (lane + 64 < wlo || lane + 64 > whi);
        mlo = __ballot(h0);
        mhi = __ballot(h1);
    }

    // scan selected blocks (uniform 1KB loads from L2-resident srt)
    while (mlo | mhi) {
        int bb;
        if (mlo) { bb = __ffsll(mlo) - 1;      mlo &= (mlo - 1); }
        else     { bb = 64 + __ffsll(mhi) - 1; mhi &= (mhi - 1); }
        const float4 pc = srt[(bb << 6) + lane];
        const float dx = p.x - pc.x, dy = p.y - pc.y, dz = p.z - pc.z;
        const float d = dx*dx + dy*dy + dz*dz;
        const unsigned long long m = __ballot(d < cm);
        APPEND(m, d, pc)
    }
    if (cnt > 0) compact(ld, lj, sd, sj, cnt, lane);
#undef APPEND

    if (lane >= 1 && lane <= KNN) idx_out[qorig * KNN + lane - 1] = lj;
}

// ---------------- layer0 GEMM: K=3 special case ----------------
__global__ __launch_bounds__(128) void gemm0_kernel(const float* __restrict__ x,
                                                    const float* __restrict__ Wc,
                                                    float* __restrict__ T) {
    __shared__ float sw[384];
    const int t = threadIdx.x;
    sw[t]       = Wc[t];
    sw[t + 128] = Wc[t + 128];
    sw[t + 256] = Wc[t + 256];
    __syncthreads();
    const int n = blockIdx.x;
    const float x0 = x[3*n+0], x1 = x[3*n+1], x2 = x[3*n+2];
    T[n*128 + t] = x0*sw[3*t+0] + x1*sw[3*t+1] + x2*sw[3*t+2];
}

// ---------------- bf16 MFMA GEMM: T(f32) = H(bf16, NxK) * Wc^T(bf16, MxK) ----------------
// Block 256 = 4 waves; wave w: rows [bx*64 + w*16, +16), cols [by*64, +64).
// Fragments: A lane l -> (row m=l&15, k=(l>>4)*8+0..7); B lane l -> (col n=l&15,
// same k); D lane l reg r -> (row (l>>4)*4+r, col l&15)  [m89-verified C/D map].
// All operands straight from L2 (H <= 2MB, Wc <= 128KB); no LDS.
__global__ __launch_bounds__(256) void gemm_bf16(const ushort* __restrict__ H,
                                                 const ushort* __restrict__ Wc,
                                                 float* __restrict__ T,
                                                 int Kk, int Mm) {
    const int l  = threadIdx.x & 63;
    const int w  = threadIdx.x >> 6;
    const int m  = l & 15;
    const int kg = l >> 4;
    const int row_t = blockIdx.x * 64 + w * 16;
    const int col0  = blockIdx.y * 64;

    f32x4v acc0 = {0.f, 0.f, 0.f, 0.f};
    f32x4v acc1 = acc0, acc2 = acc0, acc3 = acc0;

    const ushort* hp = H  + (row_t + m) * Kk + kg * 8;
    const ushort* wp = Wc + (col0 + m) * Kk + kg * 8;
    const int wstep = 16 * Kk;

    for (int k0 = 0; k0 < Kk; k0 += 32) {
        const short8v a  = *reinterpret_cast<const short8v*>(hp + k0);
        const short8v b0 = *reinterpret_cast<const short8v*>(wp + k0);
        const short8v b1 = *reinterpret_cast<const short8v*>(wp + wstep + k0);
        const short8v b2 = *reinterpret_cast<const short8v*>(wp + 2 * wstep + k0);
        const short8v b3 = *reinterpret_cast<const short8v*>(wp + 3 * wstep + k0);
        acc0 = __builtin_amdgcn_mfma_f32_16x16x32_bf16(a, b0, acc0, 0, 0, 0);
        acc1 = __builtin_amdgcn_mfma_f32_16x16x32_bf16(a, b1, acc1, 0, 0, 0);
        acc2 = __builtin_amdgcn_mfma_f32_16x16x32_bf16(a, b2, acc2, 0, 0, 0);
        acc3 = __builtin_amdgcn_mfma_f32_16x16x32_bf16(a, b3, acc3, 0, 0, 0);
    }

    const int orow = row_t + kg * 4;
#pragma unroll
    for (int r = 0; r < 4; ++r) {
        float* trow = &T[(orow + r) * Mm + col0 + m];
        trow[0]  = acc0[r];
        trow[16] = acc1[r];
        trow[32] = acc2[r];
        trow[48] = acc3[r];
    }
}

// ---------------- gather + max + bias + relu (float4/thread, optional bf16 out) ----------------
template<int O, int OUT_BF16>
__global__ __launch_bounds__(256) void maxrelu_kernel(const float* __restrict__ T,
                                                      const int* __restrict__ idx,
                                                      const float* __restrict__ bias,
                                                      void* __restrict__ outv) {
    constexpr int Q   = O / 4;
    constexpr int PPB = 256 / Q;
    constexpr int M2  = 2 * O;
    const int pi = threadIdx.x / Q;
    const int oq = threadIdx.x & (Q - 1);
    const int i  = blockIdx.x * PPB + pi;
    __shared__ int sidx[PPB * KNN];
    for (int t = threadIdx.x; t < PPB * KNN; t += 256)
        sidx[t] = idx[blockIdx.x * PPB * KNN + t];
    __syncthreads();
    const int sb = pi * KNN;
    float4 m = make_float4(-INFINITY, -INFINITY, -INFINITY, -INFINITY);
#pragma unroll
    for (int k = 0; k < KNN; ++k) {
        const float4 v = *reinterpret_cast<const float4*>(&T[sidx[sb + k] * M2 + O + oq * 4]);
        m.x = fmaxf(m.x, v.x); m.y = fmaxf(m.y, v.y);
        m.z = fmaxf(m.z, v.z); m.w = fmaxf(m.w, v.w);
    }
    const float4 b = *reinterpret_cast<const float4*>(&T[i * M2 + oq * 4]);
    const float4 bv = *reinterpret_cast<const float4*>(&bias[oq * 4]);
    float4 o;
    o.x = fmaxf(b.x + bv.x + m.x, 0.0f);
    o.y = fmaxf(b.y + bv.y + m.y, 0.0f);
    o.z = fmaxf(b.z + bv.z + m.z, 0.0f);
    o.w = fmaxf(b.w + bv.w + m.w, 0.0f);
    if (OUT_BF16) {
        const __hip_bfloat16 h0 = __float2bfloat16(o.x);
        const __hip_bfloat16 h1 = __float2bfloat16(o.y);
        const __hip_bfloat16 h2 = __float2bfloat16(o.z);
        const __hip_bfloat16 h3 = __float2bfloat16(o.w);
        ushort4 u;
        u.x = *reinterpret_cast<const ushort*>(&h0);
        u.y = *reinterpret_cast<const ushort*>(&h1);
        u.z = *reinterpret_cast<const ushort*>(&h2);
        u.w = *reinterpret_cast<const ushort*>(&h3);
        *reinterpret_cast<ushort4*>(reinterpret_cast<ushort*>(outv) + i * O + oq * 4) = u;
    } else {
        *reinterpret_cast<float4*>(reinterpret_cast<float*>(outv) + i * O + oq * 4) = o;
    }
}

extern "C" void kernel_launch(void* const* d_in, const int* in_sizes, int n_in,
                              void* d_out, int out_size, void* d_ws, size_t ws_size,
                              hipStream_t stream) {
    const float* x  = (const float*)d_in[0];
    const float* W0 = (const float*)d_in[1];
    const float* b0 = (const float*)d_in[2];
    const float* W1 = (const float*)d_in[3];
    const float* b1 = (const float*)d_in[4];
    const float* W2 = (const float*)d_in[5];
    const float* b2 = (const float*)d_in[6];
    float* out = (float*)d_out;
    char*  ws  = (char*)d_ws;

    int*            idx  = (int*)(ws + 0);             // 655360
    float*          Wc0  = (float*)(ws + 655360);      // 1536
    __hip_bfloat16* Wc1  = (__hip_bfloat16*)(ws + 656896);   // 32 KB
    __hip_bfloat16* Wc2  = (__hip_bfloat16*)(ws + 722432);   // 128 KB
    float*          bufA = (float*)(ws + 984576);      // 16 MB (T: fp32)
    void*           bufB = (void*)(ws + 17761792);     // 4 MB (h: bf16)

    // knn-phase scratch aliases bufA (dead before gemm0 writes bufA)
    float4* xq        = (float4*)bufA;                    // 128 KB @ 0
    float4* srt       = (float4*)((char*)bufA + 131072);  // 128 KB
    int*    bId       = (int*)((char*)bufA + 262144);     // 32 KB
    int*    hist_part = (int*)((char*)bufA + 294912);     // 8*16 KB = 128 KB
    int*    work      = (int*)((char*)bufA + 425984);     // 16 KB
    float4* bmin      = (float4*)((char*)bufA + 442368);  // 2 KB
    float4* bmax      = (float4*)((char*)bufA + 444416);  // 2 KB

    prep_all<<<169, 256, 0, stream>>>(x, W0, W1, W2, xq, bId, hist_part, Wc0, Wc1, Wc2);
    prefix4096<<<1, 1024, 0, stream>>>(hist_part, work);
    scatter_pts<<<32, 256, 0, stream>>>(xq, bId, work, srt);
    aabb_kernel<<<NBLK / 4, 256, 0, stream>>>(srt, bmin, bmax);
    knn_kernel<<<NPTS / 4, 256, 0, stream>>>(srt, bmin, bmax, idx);

    // layer 0: x -> T0(8192x128 f32) -> h0(8192x64 bf16)
    gemm0_kernel<<<NPTS, 128, 0, stream>>>(x, Wc0, bufA);
    maxrelu_kernel<64, 1><<<NPTS / 16, 256, 0, stream>>>(bufA, idx, b0, bufB);

    // layer 1: h0 -> T1(8192x256 f32) -> h1(8192x128 bf16)
    gemm_bf16<<<dim3(128, 4), 256, 0, stream>>>((const ushort*)bufB, (const ushort*)Wc1,
                                                bufA, 64, 256);
    maxrelu_kernel<128, 1><<<NPTS / 8, 256, 0, stream>>>(bufA, idx, b1, bufB);

    // layer 2: h1 -> T2(8192x512 f32) -> out(8192x256 f32)
    gemm_bf16<<<dim3(128, 8), 256, 0, stream>>>((const ushort*)bufB, (const ushort*)Wc2,
                                                bufA, 128, 512);
    maxrelu_kernel<256, 0><<<NPTS / 4, 256, 0, stream>>>(bufA, idx, b2, out);
}

// Round 14
// 103.689 us; speedup vs baseline: 1.5740x; 1.0524x over previous
//
#include <hip/hip_runtime.h>
#include <hip/hip_bf16.h>
#include <math.h>

#define NPTS 8192
#define KNN  20
#define NBLK (NPTS / 64)           // 128 sorted 64-blocks
#define NCELL 4096                 // 16^3 Morton cells
#define GLO  (-4.0f)
#define GINV (2.0f)

typedef __attribute__((ext_vector_type(8))) short short8v;
typedef __attribute__((ext_vector_type(4))) float f32x4v;

__device__ __forceinline__ int cellof(float v) {
    int c = (int)floorf((v - GLO) * GINV);
    return min(max(c, 0), 15);
}
__device__ __forceinline__ int spread4(int b) {
    return (b & 1) | ((b & 2) << 2) | ((b & 4) << 4) | ((b & 8) << 6);
}
// orderable encoding: unsigned compare == float compare
__device__ __forceinline__ unsigned fenc(float f) {
    unsigned u = __float_as_uint(f);
    return (u & 0x80000000u) ? ~u : (u | 0x80000000u);
}
__device__ __forceinline__ float fdec(unsigned k) {
    unsigned u = (k & 0x80000000u) ? (k & 0x7fffffffu) : ~k;
    return __uint_as_float(u);
}

// 64-lane bitonic sort, ascending by lane. Keys d, payload ji.
__device__ __forceinline__ void bitonic64(float& d, int& ji, int lane) {
#pragma unroll
    for (int k = 2; k <= 64; k <<= 1) {
#pragma unroll
        for (int j = k >> 1; j > 0; j >>= 1) {
            const float od = __shfl_xor(d, j);
            const int   oi = __shfl_xor(ji, j);
            const bool up      = ((lane & k) == 0);
            const bool lower   = ((lane & j) == 0);
            const bool takeMin = (up == lower);
            const bool sw = takeMin ? (od < d) : (od > d);
            d  = sw ? od : d;
            ji = sw ? oi : ji;
        }
    }
}

__device__ __forceinline__ void bitonic_clean64(float& d, int& ji, int lane) {
#pragma unroll
    for (int j = 32; j > 0; j >>= 1) {
        const float od = __shfl_xor(d, j);
        const int   oi = __shfl_xor(ji, j);
        const bool lower = ((lane & j) == 0);
        const bool sw = lower ? (od < d) : (od > d);
        d  = sw ? od : d;
        ji = sw ? oi : ji;
    }
}

// merge LDS hit-pool (cnt entries) into the resident sorted-64 list (ld,lj)
__device__ __forceinline__ void compact(float& ld, int& lj,
                                        const float* __restrict__ sd,
                                        const int* __restrict__ sj,
                                        int cnt, int lane) {
    __builtin_amdgcn_wave_barrier();          // order pool ds_writes before reads
    float bd = (lane < cnt) ? sd[lane] : INFINITY;
    int   bj = (lane < cnt) ? sj[lane] : -1;
    bitonic64(bd, bj, lane);
    const float rd = __shfl(bd, 63 - lane);
    const int   rj = __shfl(bj, 63 - lane);
    const bool sw = rd < ld;
    float md = sw ? rd : ld;
    int   mj = sw ? rj : lj;
    bitonic_clean64(md, mj, lane);
    ld = md; lj = mj;
}

// ---------------- weight restructure helpers ----------------
__device__ __forceinline__ void prep_w_elem(const float* __restrict__ W,
                                            float* __restrict__ Wc,
                                            int tid, int O, int C) {
    const int o = tid / C, k = tid % C;
    const float wa = W[o*2*C + k];
    const float wb = W[o*2*C + C + k];
    Wc[o*C + k]       = wa - wb;
    Wc[(O + o)*C + k] = wb;
}

__device__ __forceinline__ void prep_w_elem_b(const float* __restrict__ W,
                                              __hip_bfloat16* __restrict__ Wc,
                                              int tid, int O, int C) {
    const int o = tid / C, k = tid % C;
    const float wa = W[o*2*C + k];
    const float wb = W[o*2*C + C + k];
    Wc[o*C + k]       = __float2bfloat16(wa - wb);
    Wc[(O + o)*C + k] = __float2bfloat16(wb);
}

// ---------------- sortall: whole pre-knn chain in ONE kernel ----------------
// Block 0 (1024 thr): read x, Morton cells (regs, 8 pts/thr), LDS hist ->
// LDS prefix -> LDS-cursor scatter -> srt, with per-64-block AABB accumulated
// during scatter via LDS atomicMin/Max on order-encoded floats (no srt
// re-read -> no L1 staleness hazard). Blocks 1..8: Wc0/Wc1/Wc2 restructure.
__global__ __launch_bounds__(1024) void sortall(const float* __restrict__ x,
                                                const float* __restrict__ W0,
                                                const float* __restrict__ W1,
                                                const float* __restrict__ W2,
                                                float4* __restrict__ srt,
                                                float4* __restrict__ bming,
                                                float4* __restrict__ bmaxg,
                                                float* __restrict__ Wc0,
                                                __hip_bfloat16* __restrict__ Wc1,
                                                __hip_bfloat16* __restrict__ Wc2) {
    const int t = threadIdx.x;
    if (blockIdx.x != 0) {
        // Wc prep: flat range over 192 + 8192 + 32768 elements
        for (int g = (blockIdx.x - 1) * 1024 + t; g < 192 + 8192 + 32768; g += 8 * 1024) {
            if (g < 192)             prep_w_elem(W0, Wc0, g, 64, 3);
            else if (g < 192 + 8192) prep_w_elem_b(W1, Wc1, g - 192, 128, 64);
            else                     prep_w_elem_b(W2, Wc2, g - 8384, 256, 128);
        }
        return;
    }
    __shared__ int lh[NCELL];
    __shared__ int lw[NCELL];
    __shared__ int ls[1024];
    __shared__ unsigned abn[NBLK * 3], abx[NBLK * 3];

    float px[8], py[8], pz[8];
    int   pc[8];
    for (int u = t; u < NCELL; u += 1024) { lh[u] = 0; }
    for (int u = t; u < NBLK * 3; u += 1024) { abn[u] = 0xFFFFFFFFu; abx[u] = 0u; }
    __syncthreads();
#pragma unroll
    for (int u = 0; u < 8; ++u) {
        const int i = u * 1024 + t;
        const float a = x[3*i+0], b = x[3*i+1], c = x[3*i+2];
        px[u] = a; py[u] = b; pz[u] = c;
        pc[u] = spread4(cellof(a)) | (spread4(cellof(b)) << 1) | (spread4(cellof(c)) << 2);
        atomicAdd(&lh[pc[u]], 1);
    }
    __syncthreads();
    // exclusive prefix over 4096 cells (4/thread + 1024-scan)
    const int h0 = lh[4*t+0], h1 = lh[4*t+1], h2 = lh[4*t+2], h3 = lh[4*t+3];
    const int s0 = h0, s1 = s0 + h1, s2 = s1 + h2, s3 = s2 + h3;
    ls[t] = s3;
    __syncthreads();
    for (int off = 1; off < 1024; off <<= 1) {
        const int uu = (t >= off) ? ls[t - off] : 0;
        __syncthreads();
        ls[t] += uu;
        __syncthreads();
    }
    const int excl = ls[t] - s3;
    lw[4*t+0] = excl;      lw[4*t+1] = excl + s0;
    lw[4*t+2] = excl + s1; lw[4*t+3] = excl + s2;
    __syncthreads();
#pragma unroll
    for (int u = 0; u < 8; ++u) {
        const int i = u * 1024 + t;
        const int pos = atomicAdd(&lw[pc[u]], 1);
        srt[pos] = make_float4(px[u], py[u], pz[u], __int_as_float(i));
        const int blk = pos >> 6;
        atomicMin(&abn[blk*3+0], fenc(px[u])); atomicMax(&abx[blk*3+0], fenc(px[u]));
        atomicMin(&abn[blk*3+1], fenc(py[u])); atomicMax(&abx[blk*3+1], fenc(py[u]));
        atomicMin(&abn[blk*3+2], fenc(pz[u])); atomicMax(&abx[blk*3+2], fenc(pz[u]));
    }
    __syncthreads();
    if (t < NBLK) {
        bming[t] = make_float4(fdec(abn[3*t+0]), fdec(abn[3*t+1]), fdec(abn[3*t+2]), 0.0f);
        bmaxg[t] = make_float4(fdec(abx[3*t+0]), fdec(abx[3*t+1]), fdec(abx[3*t+2]), 0.0f);
    }
}

// ---------------- KNN: Morton init + window pre-pass + AABB-screened scan ----------------
__global__ __launch_bounds__(256) void knn_kernel(const float4* __restrict__ srt,
                                                  const float4* __restrict__ bmin,
                                                  const float4* __restrict__ bmax,
                                                  int* __restrict__ idx_out) {
    __shared__ float sdp[4][64];
    __shared__ int   sjp[4][64];
    const int lane = threadIdx.x & 63;
    const int wv   = threadIdx.x >> 6;
    const int s    = blockIdx.x * 4 + wv;
    float* sd = sdp[wv];
    int*   sj = sjp[wv];

    const float4 p = srt[s];
    const int qorig = __float_as_int(p.w);
    const int bq = s >> 6;

    // init: own Morton block (contains self, d=0 -> lane 0 after final sort)
    float ld, cm;
    int lj;
    {
        const float4 c = srt[(bq << 6) + lane];
        const float dx = p.x - c.x, dy = p.y - c.y, dz = p.z - c.z;
        ld = dx*dx + dy*dy + dz*dz;
        lj = __float_as_int(c.w);
        bitonic64(ld, lj, lane);
        cm = __shfl(ld, KNN);                 // 21st incl self = 20th excl
    }
    int cnt = 0;

#define APPEND(M, D, C4)                                                      \
    if (M) {                                                                  \
        const int tot = __popcll(M);                                          \
        if (cnt + tot > 64) {                                                 \
            compact(ld, lj, sd, sj, cnt, lane);                               \
            cm = __shfl(ld, KNN);                                             \
            cnt = 0;                                                          \
        }                                                                     \
        const int below = __builtin_amdgcn_mbcnt_hi(                          \
            (unsigned)((M) >> 32),                                            \
            __builtin_amdgcn_mbcnt_lo((unsigned)(M), 0));                     \
        const bool h = ((M) >> lane) & 1ull;                                  \
        if (h) { sd[cnt + below] = D; sj[cnt + below] = __float_as_int(C4.w); } \
        cnt += tot;                                                           \
    }

    // pre-pass: Morton window (direct from L2), excluding own block
    const int wlo = max(bq - 3, 0);
    const int whi = min(bq + 3, NBLK - 1);
    for (int bb = wlo; bb <= whi; ++bb) {
        if (bb == bq) continue;
        const float4 pc = srt[(bb << 6) + lane];
        const float dx = p.x - pc.x, dy = p.y - pc.y, dz = p.z - pc.z;
        const float d = dx*dx + dy*dy + dz*dz;
        const unsigned long long m = __ballot(d < cm);
        APPEND(m, d, pc)
    }
    if (cnt > 0) { compact(ld, lj, sd, sj, cnt, lane); cm = __shfl(ld, KNN); cnt = 0; }

    // AABB screen: lane handles blocks lane and lane+64
    unsigned long long mlo, mhi;
    {
        const float4 n0 = bmin[lane],      x0 = bmax[lane];
        const float4 n1 = bmin[lane + 64], x1 = bmax[lane + 64];
        float ax = fmaxf(fmaxf(n0.x - p.x, p.x - x0.x), 0.0f);
        float ay = fmaxf(fmaxf(n0.y - p.y, p.y - x0.y), 0.0f);
        float az = fmaxf(fmaxf(n0.z - p.z, p.z - x0.z), 0.0f);
        const float lb0 = ax*ax + ay*ay + az*az;
        ax = fmaxf(fmaxf(n1.x - p.x, p.x - x1.x), 0.0f);
        ay = fmaxf(fmaxf(n1.y - p.y, p.y - x1.y), 0.0f);
        az = fmaxf(fmaxf(n1.z - p.z, p.z - x1.z), 0.0f);
        const float lb1 = ax*ax + ay*ay + az*az;
        const bool h0 = (lb0 < cm) && (lane < wlo || lane > whi);
        const bool h1 = (lb1 < cm) && (lane + 64 < wlo || lane + 64 > whi);
        mlo = __ballot(h0);
        mhi = __ballot(h1);
    }

    // scan selected blocks (uniform 1KB loads from L2-resident srt)
    while (mlo | mhi) {
        int bb;
        if (mlo) { bb = __ffsll(mlo) - 1;      mlo &= (mlo - 1); }
        else     { bb = 64 + __ffsll(mhi) - 1; mhi &= (mhi - 1); }
        const float4 pc = srt[(bb << 6) + lane];
        const float dx = p.x - pc.x, dy = p.y - pc.y, dz = p.z - pc.z;
        const float d = dx*dx + dy*dy + dz*dz;
        const unsigned long long m = __ballot(d < cm);
        APPEND(m, d, pc)
    }
    if (cnt > 0) compact(ld, lj, sd, sj, cnt, lane);
#undef APPEND

    if (lane >= 1 && lane <= KNN) idx_out[qorig * KNN + lane - 1] = lj;
}

// ---------------- layer0 GEMM: K=3 special case ----------------
__global__ __launch_bounds__(128) void gemm0_kernel(const float* __restrict__ x,
                                                    const float* __restrict__ Wc,
                                                    float* __restrict__ T) {
    __shared__ float sw[384];
    const int t = threadIdx.x;
    sw[t]       = Wc[t];
    sw[t + 128] = Wc[t + 128];
    sw[t + 256] = Wc[t + 256];
    __syncthreads();
    const int n = blockIdx.x;
    const float x0 = x[3*n+0], x1 = x[3*n+1], x2 = x[3*n+2];
    T[n*128 + t] = x0*sw[3*t+0] + x1*sw[3*t+1] + x2*sw[3*t+2];
}

// ---------------- bf16 MFMA GEMM: T(f32) = H(bf16, NxK) * Wc^T(bf16, MxK) ----------------
__global__ __launch_bounds__(256) void gemm_bf16(const ushort* __restrict__ H,
                                                 const ushort* __restrict__ Wc,
                                                 float* __restrict__ T,
                                                 int Kk, int Mm) {
    const int l  = threadIdx.x & 63;
    const int w  = threadIdx.x >> 6;
    const int m  = l & 15;
    const int kg = l >> 4;
    const int row_t = blockIdx.x * 64 + w * 16;
    const int col0  = blockIdx.y * 64;

    f32x4v acc0 = {0.f, 0.f, 0.f, 0.f};
    f32x4v acc1 = acc0, acc2 = acc0, acc3 = acc0;

    const ushort* hp = H  + (row_t + m) * Kk + kg * 8;
    const ushort* wp = Wc + (col0 + m) * Kk + kg * 8;
    const int wstep = 16 * Kk;

    for (int k0 = 0; k0 < Kk; k0 += 32) {
        const short8v a  = *reinterpret_cast<const short8v*>(hp + k0);
        const short8v b0 = *reinterpret_cast<const short8v*>(wp + k0);
        const short8v b1 = *reinterpret_cast<const short8v*>(wp + wstep + k0);
        const short8v b2 = *reinterpret_cast<const short8v*>(wp + 2 * wstep + k0);
        const short8v b3 = *reinterpret_cast<const short8v*>(wp + 3 * wstep + k0);
        acc0 = __builtin_amdgcn_mfma_f32_16x16x32_bf16(a, b0, acc0, 0, 0, 0);
        acc1 = __builtin_amdgcn_mfma_f32_16x16x32_bf16(a, b1, acc1, 0, 0, 0);
        acc2 = __builtin_amdgcn_mfma_f32_16x16x32_bf16(a, b2, acc2, 0, 0, 0);
        acc3 = __builtin_amdgcn_mfma_f32_16x16x32_bf16(a, b3, acc3, 0, 0, 0);
    }

    const int orow = row_t + kg * 4;
#pragma unroll
    for (int r = 0; r < 4; ++r) {
        float* trow = &T[(orow + r) * Mm + col0 + m];
        trow[0]  = acc0[r];
        trow[16] = acc1[r];
        trow[32] = acc2[r];
        trow[48] = acc3[r];
    }
}

// ---------------- gather + max + bias + relu (float4/thread, optional bf16 out) ----------------
template<int O, int OUT_BF16>
__global__ __launch_bounds__(256) void maxrelu_kernel(const float* __restrict__ T,
                                                      const int* __restrict__ idx,
                                                      const float* __restrict__ bias,
                                                      void* __restrict__ outv) {
    constexpr int Q   = O / 4;
    constexpr int PPB = 256 / Q;
    constexpr int M2  = 2 * O;
    const int pi = threadIdx.x / Q;
    const int oq = threadIdx.x & (Q - 1);
    const int i  = blockIdx.x * PPB + pi;
    __shared__ int sidx[PPB * KNN];
    for (int t = threadIdx.x; t < PPB * KNN; t += 256)
        sidx[t] = idx[blockIdx.x * PPB * KNN + t];
    __syncthreads();
    const int sb = pi * KNN;
    float4 m = make_float4(-INFINITY, -INFINITY, -INFINITY, -INFINITY);
#pragma unroll
    for (int k = 0; k < KNN; ++k) {
        const float4 v = *reinterpret_cast<const float4*>(&T[sidx[sb + k] * M2 + O + oq * 4]);
        m.x = fmaxf(m.x, v.x); m.y = fmaxf(m.y, v.y);
        m.z = fmaxf(m.z, v.z); m.w = fmaxf(m.w, v.w);
    }
    const float4 b = *reinterpret_cast<const float4*>(&T[i * M2 + oq * 4]);
    const float4 bv = *reinterpret_cast<const float4*>(&bias[oq * 4]);
    float4 o;
    o.x = fmaxf(b.x + bv.x + m.x, 0.0f);
    o.y = fmaxf(b.y + bv.y + m.y, 0.0f);
    o.z = fmaxf(b.z + bv.z + m.z, 0.0f);
    o.w = fmaxf(b.w + bv.w + m.w, 0.0f);
    if (OUT_BF16) {
        const __hip_bfloat16 h0 = __float2bfloat16(o.x);
        const __hip_bfloat16 h1 = __float2bfloat16(o.y);
        const __hip_bfloat16 h2 = __float2bfloat16(o.z);
        const __hip_bfloat16 h3 = __float2bfloat16(o.w);
        ushort4 u;
        u.x = *reinterpret_cast<const ushort*>(&h0);
        u.y = *reinterpret_cast<const ushort*>(&h1);
        u.z = *reinterpret_cast<const ushort*>(&h2);
        u.w = *reinterpret_cast<const ushort*>(&h3);
        *reinterpret_cast<ushort4*>(reinterpret_cast<ushort*>(outv) + i * O + oq * 4) = u;
    } else {
        *reinterpret_cast<float4*>(reinterpret_cast<float*>(outv) + i * O + oq * 4) = o;
    }
}

extern "C" void kernel_launch(void* const* d_in, const int* in_sizes, int n_in,
                              void* d_out, int out_size, void* d_ws, size_t ws_size,
                              hipStream_t stream) {
    const float* x  = (const float*)d_in[0];
    const float* W0 = (const float*)d_in[1];
    const float* b0 = (const float*)d_in[2];
    const float* W1 = (const float*)d_in[3];
    const float* b1 = (const float*)d_in[4];
    const float* W2 = (const float*)d_in[5];
    const float* b2 = (const float*)d_in[6];
    float* out = (float*)d_out;
    char*  ws  = (char*)d_ws;

    int*            idx  = (int*)(ws + 0);                   // 655360
    float*          Wc0  = (float*)(ws + 655360);            // 1536
    __hip_bfloat16* Wc1  = (__hip_bfloat16*)(ws + 656896);   // 32 KB
    __hip_bfloat16* Wc2  = (__hip_bfloat16*)(ws + 722432);   // 128 KB
    float*          bufA = (float*)(ws + 984576);            // 16 MB (T: fp32)
    void*           bufB = (void*)(ws + 17761792);           // 4 MB (h: bf16)

    // knn-phase scratch aliases bufA (dead before gemm0 writes bufA)
    float4* srt  = (float4*)((char*)bufA + 131072);          // 128 KB
    float4* bmin = (float4*)((char*)bufA + 442368);          // 2 KB
    float4* bmax = (float4*)((char*)bufA + 444416);          // 2 KB

    // whole pre-knn chain (sort + AABB + weight restructure) in one kernel
    sortall<<<9, 1024, 0, stream>>>(x, W0, W1, W2, srt, bmin, bmax, Wc0, Wc1, Wc2);
    knn_kernel<<<NPTS / 4, 256, 0, stream>>>(srt, bmin, bmax, idx);

    // layer 0: x -> T0(8192x128 f32) -> h0(8192x64 bf16)
    gemm0_kernel<<<NPTS, 128, 0, stream>>>(x, Wc0, bufA);
    maxrelu_kernel<64, 1><<<NPTS / 16, 256, 0, stream>>>(bufA, idx, b0, bufB);

    // layer 1: h0 -> T1(8192x256 f32) -> h1(8192x128 bf16)
    gemm_bf16<<<dim3(128, 4), 256, 0, stream>>>((const ushort*)bufB, (const ushort*)Wc1,
                                                bufA, 64, 256);
    maxrelu_kernel<128, 1><<<NPTS / 8, 256, 0, stream>>>(bufA, idx, b1, bufB);

    // layer 2: h1 -> T2(8192x512 f32) -> out(8192x256 f32)
    gemm_bf16<<<dim3(128, 8), 256, 0, stream>>>((const ushort*)bufB, (const ushort*)Wc2,
                                                bufA, 128, 512);
    maxrelu_kernel<256, 0><<<NPTS / 4, 256, 0, stream>>>(bufA, idx, b2, out);
}

// Round 15
// 96.445 us; speedup vs baseline: 1.6922x; 1.0751x over previous
//
#include <hip/hip_runtime.h>
#include <hip/hip_bf16.h>
#include <math.h>

#define NPTS 8192
#define KNN  20
#define NBLK (NPTS / 64)           // 128 sorted 64-blocks
#define NCELL 4096                 // 16^3 Morton cells
#define GLO  (-4.0f)
#define GINV (2.0f)

typedef __attribute__((ext_vector_type(8))) short short8v;
typedef __attribute__((ext_vector_type(4))) float f32x4v;

__device__ __forceinline__ int cellof(float v) {
    int c = (int)floorf((v - GLO) * GINV);
    return min(max(c, 0), 15);
}
__device__ __forceinline__ int spread4(int b) {
    return (b & 1) | ((b & 2) << 2) | ((b & 4) << 4) | ((b & 8) << 6);
}
// orderable encoding: unsigned compare == float compare
__device__ __forceinline__ unsigned fenc(float f) {
    unsigned u = __float_as_uint(f);
    return (u & 0x80000000u) ? ~u : (u | 0x80000000u);
}
__device__ __forceinline__ float fdec(unsigned k) {
    unsigned u = (k & 0x80000000u) ? (k & 0x7fffffffu) : ~k;
    return __uint_as_float(u);
}

// 64-lane bitonic sort, ascending by lane. Keys d, payload ji.
__device__ __forceinline__ void bitonic64(float& d, int& ji, int lane) {
#pragma unroll
    for (int k = 2; k <= 64; k <<= 1) {
#pragma unroll
        for (int j = k >> 1; j > 0; j >>= 1) {
            const float od = __shfl_xor(d, j);
            const int   oi = __shfl_xor(ji, j);
            const bool up      = ((lane & k) == 0);
            const bool lower   = ((lane & j) == 0);
            const bool takeMin = (up == lower);
            const bool sw = takeMin ? (od < d) : (od > d);
            d  = sw ? od : d;
            ji = sw ? oi : ji;
        }
    }
}

__device__ __forceinline__ void bitonic_clean64(float& d, int& ji, int lane) {
#pragma unroll
    for (int j = 32; j > 0; j >>= 1) {
        const float od = __shfl_xor(d, j);
        const int   oi = __shfl_xor(ji, j);
        const bool lower = ((lane & j) == 0);
        const bool sw = lower ? (od < d) : (od > d);
        d  = sw ? od : d;
        ji = sw ? oi : ji;
    }
}

// merge LDS hit-pool (cnt entries) into the resident sorted-64 list (ld,lj)
__device__ __forceinline__ void compact(float& ld, int& lj,
                                        const float* __restrict__ sd,
                                        const int* __restrict__ sj,
                                        int cnt, int lane) {
    __builtin_amdgcn_wave_barrier();          // order pool ds_writes before reads
    float bd = (lane < cnt) ? sd[lane] : INFINITY;
    int   bj = (lane < cnt) ? sj[lane] : -1;
    bitonic64(bd, bj, lane);
    const float rd = __shfl(bd, 63 - lane);
    const int   rj = __shfl(bj, 63 - lane);
    const bool sw = rd < ld;
    float md = sw ? rd : ld;
    int   mj = sw ? rj : lj;
    bitonic_clean64(md, mj, lane);
    ld = md; lj = mj;
}

// ---------------- weight restructure helpers ----------------
__device__ __forceinline__ void prep_w_elem(const float* __restrict__ W,
                                            float* __restrict__ Wc,
                                            int tid, int O, int C) {
    const int o = tid / C, k = tid % C;
    const float wa = W[o*2*C + k];
    const float wb = W[o*2*C + C + k];
    Wc[o*C + k]       = wa - wb;
    Wc[(O + o)*C + k] = wb;
}

__device__ __forceinline__ void prep_w_elem_b(const float* __restrict__ W,
                                              __hip_bfloat16* __restrict__ Wc,
                                              int tid, int O, int C) {
    const int o = tid / C, k = tid % C;
    const float wa = W[o*2*C + k];
    const float wb = W[o*2*C + C + k];
    Wc[o*C + k]       = __float2bfloat16(wa - wb);
    Wc[(O + o)*C + k] = __float2bfloat16(wb);
}

// ---------------- sortall: whole pre-knn chain in ONE kernel ----------------
__global__ __launch_bounds__(1024) void sortall(const float* __restrict__ x,
                                                const float* __restrict__ W0,
                                                const float* __restrict__ W1,
                                                const float* __restrict__ W2,
                                                float4* __restrict__ srt,
                                                float4* __restrict__ bming,
                                                float4* __restrict__ bmaxg,
                                                float* __restrict__ Wc0,
                                                __hip_bfloat16* __restrict__ Wc1,
                                                __hip_bfloat16* __restrict__ Wc2) {
    const int t = threadIdx.x;
    if (blockIdx.x != 0) {
        for (int g = (blockIdx.x - 1) * 1024 + t; g < 192 + 8192 + 32768; g += 8 * 1024) {
            if (g < 192)             prep_w_elem(W0, Wc0, g, 64, 3);
            else if (g < 192 + 8192) prep_w_elem_b(W1, Wc1, g - 192, 128, 64);
            else                     prep_w_elem_b(W2, Wc2, g - 8384, 256, 128);
        }
        return;
    }
    __shared__ int lh[NCELL];
    __shared__ int lw[NCELL];
    __shared__ int ls[1024];
    __shared__ unsigned abn[NBLK * 3], abx[NBLK * 3];

    float px[8], py[8], pz[8];
    int   pc[8];
    for (int u = t; u < NCELL; u += 1024) { lh[u] = 0; }
    for (int u = t; u < NBLK * 3; u += 1024) { abn[u] = 0xFFFFFFFFu; abx[u] = 0u; }
    __syncthreads();
#pragma unroll
    for (int u = 0; u < 8; ++u) {
        const int i = u * 1024 + t;
        const float a = x[3*i+0], b = x[3*i+1], c = x[3*i+2];
        px[u] = a; py[u] = b; pz[u] = c;
        pc[u] = spread4(cellof(a)) | (spread4(cellof(b)) << 1) | (spread4(cellof(c)) << 2);
        atomicAdd(&lh[pc[u]], 1);
    }
    __syncthreads();
    const int h0 = lh[4*t+0], h1 = lh[4*t+1], h2 = lh[4*t+2], h3 = lh[4*t+3];
    const int s0 = h0, s1 = s0 + h1, s2 = s1 + h2, s3 = s2 + h3;
    ls[t] = s3;
    __syncthreads();
    for (int off = 1; off < 1024; off <<= 1) {
        const int uu = (t >= off) ? ls[t - off] : 0;
        __syncthreads();
        ls[t] += uu;
        __syncthreads();
    }
    const int excl = ls[t] - s3;
    lw[4*t+0] = excl;      lw[4*t+1] = excl + s0;
    lw[4*t+2] = excl + s1; lw[4*t+3] = excl + s2;
    __syncthreads();
#pragma unroll
    for (int u = 0; u < 8; ++u) {
        const int i = u * 1024 + t;
        const int pos = atomicAdd(&lw[pc[u]], 1);
        srt[pos] = make_float4(px[u], py[u], pz[u], __int_as_float(i));
        const int blk = pos >> 6;
        atomicMin(&abn[blk*3+0], fenc(px[u])); atomicMax(&abx[blk*3+0], fenc(px[u]));
        atomicMin(&abn[blk*3+1], fenc(py[u])); atomicMax(&abx[blk*3+1], fenc(py[u]));
        atomicMin(&abn[blk*3+2], fenc(pz[u])); atomicMax(&abx[blk*3+2], fenc(pz[u]));
    }
    __syncthreads();
    if (t < NBLK) {
        bming[t] = make_float4(fdec(abn[3*t+0]), fdec(abn[3*t+1]), fdec(abn[3*t+2]), 0.0f);
        bmaxg[t] = make_float4(fdec(abx[3*t+0]), fdec(abx[3*t+1]), fdec(abx[3*t+2]), 0.0f);
    }
}

// ---------------- KNN: Morton init + prefetched window pre-pass + 2-deep AABB scan ----------------
__global__ __launch_bounds__(256) void knn_kernel(const float4* __restrict__ srt,
                                                  const float4* __restrict__ bmin,
                                                  const float4* __restrict__ bmax,
                                                  int* __restrict__ idx_out) {
    __shared__ float sdp[4][64];
    __shared__ int   sjp[4][64];
    const int lane = threadIdx.x & 63;
    const int wv   = threadIdx.x >> 6;
    const int s    = blockIdx.x * 4 + wv;
    float* sd = sdp[wv];
    int*   sj = sjp[wv];

    const float4 p = srt[s];
    const int qorig = __float_as_int(p.w);
    const int bq = s >> 6;
    const int wlo = max(bq - 3, 0);
    const int whi = min(bq + 3, NBLK - 1);

    // prefetch: own block + all 6 window blocks issued together (MLP=7)
    const float4 own = srt[(bq << 6) + lane];
    float4 wb[6];
    bool   wvalid[6];
#pragma unroll
    for (int j = 0; j < 6; ++j) {
        const int off = (j < 3) ? (j - 3) : (j - 2);   // -3,-2,-1,1,2,3
        const int bb = bq + off;
        wvalid[j] = (bb >= 0) && (bb < NBLK);
        const int bc = min(max(bb, 0), NBLK - 1);
        wb[j] = srt[(bc << 6) + lane];
    }

    // init: own Morton block (contains self, d=0 -> lane 0 after final sort)
    float ld, cm;
    int lj;
    {
        const float dx = p.x - own.x, dy = p.y - own.y, dz = p.z - own.z;
        ld = dx*dx + dy*dy + dz*dz;
        lj = __float_as_int(own.w);
        bitonic64(ld, lj, lane);
        cm = __shfl(ld, KNN);                 // 21st incl self = 20th excl
    }
    int cnt = 0;

#define APPEND(M, D, C4)                                                      \
    if (M) {                                                                  \
        const int tot = __popcll(M);                                          \
        if (cnt + tot > 64) {                                                 \
            compact(ld, lj, sd, sj, cnt, lane);                               \
            cm = __shfl(ld, KNN);                                             \
            cnt = 0;                                                          \
        }                                                                     \
        const int below = __builtin_amdgcn_mbcnt_hi(                          \
            (unsigned)((M) >> 32),                                            \
            __builtin_amdgcn_mbcnt_lo((unsigned)(M), 0));                     \
        const bool h = ((M) >> lane) & 1ull;                                  \
        if (h) { sd[cnt + below] = D; sj[cnt + below] = __float_as_int(C4.w); } \
        cnt += tot;                                                           \
    }

    // pre-pass over prefetched window blocks (no serial load latency)
#pragma unroll
    for (int j = 0; j < 6; ++j) {
        const float dx = p.x - wb[j].x, dy = p.y - wb[j].y, dz = p.z - wb[j].z;
        const float d = dx*dx + dy*dy + dz*dz;
        const unsigned long long m = __ballot(wvalid[j] && (d < cm));
        APPEND(m, d, wb[j])
    }
    if (cnt > 0) { compact(ld, lj, sd, sj, cnt, lane); cm = __shfl(ld, KNN); cnt = 0; }

    // AABB screen: lane handles blocks lane and lane+64
    unsigned long long mlo, mhi;
    {
        const float4 n0 = bmin[lane],      x0 = bmax[lane];
        const float4 n1 = bmin[lane + 64], x1 = bmax[lane + 64];
        float ax = fmaxf(fmaxf(n0.x - p.x, p.x - x0.x), 0.0f);
        float ay = fmaxf(fmaxf(n0.y - p.y, p.y - x0.y), 0.0f);
        float az = fmaxf(fmaxf(n0.z - p.z, p.z - x0.z), 0.0f);
        const float lb0 = ax*ax + ay*ay + az*az;
        ax = fmaxf(fmaxf(n1.x - p.x, p.x - x1.x), 0.0f);
        ay = fmaxf(fmaxf(n1.y - p.y, p.y - x1.y), 0.0f);
        az = fmaxf(fmaxf(n1.z - p.z, p.z - x1.z), 0.0f);
        const float lb1 = ax*ax + ay*ay + az*az;
        const bool h0 = (lb0 < cm) && (lane < wlo || lane > whi);
        const bool h1 = (lb1 < cm) && (lane + 64 < wlo || lane + 64 > whi);
        mlo = __ballot(h0);
        mhi = __ballot(h1);
    }

    // 2-deep pipelined scan of selected blocks
    while (mlo | mhi) {
        int bb0;
        if (mlo) { bb0 = __ffsll(mlo) - 1;      mlo &= (mlo - 1); }
        else     { bb0 = 64 + __ffsll(mhi) - 1; mhi &= (mhi - 1); }
        const bool has1 = (mlo | mhi) != 0;
        int bb1 = bb0;
        if (has1) {
            if (mlo) { bb1 = __ffsll(mlo) - 1;      mlo &= (mlo - 1); }
            else     { bb1 = 64 + __ffsll(mhi) - 1; mhi &= (mhi - 1); }
        }
        const float4 c0 = srt[(bb0 << 6) + lane];
        const float4 c1 = srt[(bb1 << 6) + lane];
        const float dx0 = p.x - c0.x, dy0 = p.y - c0.y, dz0 = p.z - c0.z;
        const float d0 = dx0*dx0 + dy0*dy0 + dz0*dz0;
        const float dx1 = p.x - c1.x, dy1 = p.y - c1.y, dz1 = p.z - c1.z;
        const float d1 = dx1*dx1 + dy1*dy1 + dz1*dz1;
        const unsigned long long m0 = __ballot(d0 < cm);
        APPEND(m0, d0, c0)
        const unsigned long long m1 = __ballot(has1 && (d1 < cm));
        APPEND(m1, d1, c1)
    }
    if (cnt > 0) compact(ld, lj, sd, sj, cnt, lane);
#undef APPEND

    if (lane >= 1 && lane <= KNN) idx_out[qorig * KNN + lane - 1] = lj;
}

// ---------------- fused layer 0: per-neighbor K=3 dots + max + bias + relu -> bf16 ----------------
// 16 points/block, 16 threads/point (4 channels each). Neighbor coords staged
// in LDS; u-weights (Wb rows for this thread's 4 channels) hoisted to regs.
__global__ __launch_bounds__(256) void layer0_fused(const float* __restrict__ x,
                                                    const float* __restrict__ Wc0,
                                                    const float* __restrict__ bias,
                                                    const int* __restrict__ idx,
                                                    ushort* __restrict__ out) {
    __shared__ float sw[384];        // [128 rows][3]: rows 0..63 = Wa-Wb, 64..127 = Wb
    __shared__ int   sidx[16 * KNN];
    __shared__ float sxj[16 * KNN * 3];
    const int t = threadIdx.x;
    for (int u = t; u < 384; u += 256) sw[u] = Wc0[u];
    for (int u = t; u < 16 * KNN; u += 256) sidx[u] = idx[blockIdx.x * 16 * KNN + u];
    __syncthreads();
    for (int u = t; u < 16 * KNN; u += 256) {
        const int j = sidx[u];
        sxj[u*3+0] = x[3*j+0];
        sxj[u*3+1] = x[3*j+1];
        sxj[u*3+2] = x[3*j+2];
    }
    __syncthreads();

    const int pi = t >> 4;           // point in block
    const int oq = t & 15;           // channel quad
    const int i  = blockIdx.x * 16 + pi;
    const float xi0 = x[3*i+0], xi1 = x[3*i+1], xi2 = x[3*i+2];

    // hoist u-weights (Wb) for channels o = oq*4..oq*4+3
    float uw[4][3], base[4];
#pragma unroll
    for (int c = 0; c < 4; ++c) {
        const int o = oq * 4 + c;
        base[c] = xi0*sw[3*o+0] + xi1*sw[3*o+1] + xi2*sw[3*o+2] + bias[o];
        uw[c][0] = sw[3*(64+o)+0];
        uw[c][1] = sw[3*(64+o)+1];
        uw[c][2] = sw[3*(64+o)+2];
    }
    float m0 = -INFINITY, m1 = -INFINITY, m2 = -INFINITY, m3 = -INFINITY;
    const int sb = pi * KNN * 3;
#pragma unroll
    for (int k = 0; k < KNN; ++k) {
        const float xj0 = sxj[sb + k*3 + 0];
        const float xj1 = sxj[sb + k*3 + 1];
        const float xj2 = sxj[sb + k*3 + 2];
        m0 = fmaxf(m0, xj0*uw[0][0] + xj1*uw[0][1] + xj2*uw[0][2]);
        m1 = fmaxf(m1, xj0*uw[1][0] + xj1*uw[1][1] + xj2*uw[1][2]);
        m2 = fmaxf(m2, xj0*uw[2][0] + xj1*uw[2][1] + xj2*uw[2][2]);
        m3 = fmaxf(m3, xj0*uw[3][0] + xj1*uw[3][1] + xj2*uw[3][2]);
    }
    const float o0 = fmaxf(base[0] + m0, 0.0f);
    const float o1 = fmaxf(base[1] + m1, 0.0f);
    const float o2 = fmaxf(base[2] + m2, 0.0f);
    const float o3 = fmaxf(base[3] + m3, 0.0f);
    const __hip_bfloat16 h0 = __float2bfloat16(o0);
    const __hip_bfloat16 h1 = __float2bfloat16(o1);
    const __hip_bfloat16 h2 = __float2bfloat16(o2);
    const __hip_bfloat16 h3 = __float2bfloat16(o3);
    ushort4 u;
    u.x = *reinterpret_cast<const ushort*>(&h0);
    u.y = *reinterpret_cast<const ushort*>(&h1);
    u.z = *reinterpret_cast<const ushort*>(&h2);
    u.w = *reinterpret_cast<const ushort*>(&h3);
    *reinterpret_cast<ushort4*>(out + i * 64 + oq * 4) = u;
}

// ---------------- bf16 MFMA GEMM: T(f32) = H(bf16, NxK) * Wc^T(bf16, MxK) ----------------
__global__ __launch_bounds__(256) void gemm_bf16(const ushort* __restrict__ H,
                                                 const ushort* __restrict__ Wc,
                                                 float* __restrict__ T,
                                                 int Kk, int Mm) {
    const int l  = threadIdx.x & 63;
    const int w  = threadIdx.x >> 6;
    const int m  = l & 15;
    const int kg = l >> 4;
    const int row_t = blockIdx.x * 64 + w * 16;
    const int col0  = blockIdx.y * 64;

    f32x4v acc0 = {0.f, 0.f, 0.f, 0.f};
    f32x4v acc1 = acc0, acc2 = acc0, acc3 = acc0;

    const ushort* hp = H  + (row_t + m) * Kk + kg * 8;
    const ushort* wp = Wc + (col0 + m) * Kk + kg * 8;
    const int wstep = 16 * Kk;

    for (int k0 = 0; k0 < Kk; k0 += 32) {
        const short8v a  = *reinterpret_cast<const short8v*>(hp + k0);
        const short8v b0 = *reinterpret_cast<const short8v*>(wp + k0);
        const short8v b1 = *reinterpret_cast<const short8v*>(wp + wstep + k0);
        const short8v b2 = *reinterpret_cast<const short8v*>(wp + 2 * wstep + k0);
        const short8v b3 = *reinterpret_cast<const short8v*>(wp + 3 * wstep + k0);
        acc0 = __builtin_amdgcn_mfma_f32_16x16x32_bf16(a, b0, acc0, 0, 0, 0);
        acc1 = __builtin_amdgcn_mfma_f32_16x16x32_bf16(a, b1, acc1, 0, 0, 0);
        acc2 = __builtin_amdgcn_mfma_f32_16x16x32_bf16(a, b2, acc2, 0, 0, 0);
        acc3 = __builtin_amdgcn_mfma_f32_16x16x32_bf16(a, b3, acc3, 0, 0, 0);
    }

    const int orow = row_t + kg * 4;
#pragma unroll
    for (int r = 0; r < 4; ++r) {
        float* trow = &T[(orow + r) * Mm + col0 + m];
        trow[0]  = acc0[r];
        trow[16] = acc1[r];
        trow[32] = acc2[r];
        trow[48] = acc3[r];
    }
}

// ---------------- gather + max + bias + relu (float4/thread, optional bf16 out) ----------------
template<int O, int OUT_BF16>
__global__ __launch_bounds__(256) void maxrelu_kernel(const float* __restrict__ T,
                                                      const int* __restrict__ idx,
                                                      const float* __restrict__ bias,
                                                      void* __restrict__ outv) {
    constexpr int Q   = O / 4;
    constexpr int PPB = 256 / Q;
    constexpr int M2  = 2 * O;
    const int pi = threadIdx.x / Q;
    const int oq = threadIdx.x & (Q - 1);
    const int i  = blockIdx.x * PPB + pi;
    __shared__ int sidx[PPB * KNN];
    for (int t = threadIdx.x; t < PPB * KNN; t += 256)
        sidx[t] = idx[blockIdx.x * PPB * KNN + t];
    __syncthreads();
    const int sb = pi * KNN;
    float4 m = make_float4(-INFINITY, -INFINITY, -INFINITY, -INFINITY);
#pragma unroll
    for (int k = 0; k < KNN; ++k) {
        const float4 v = *reinterpret_cast<const float4*>(&T[sidx[sb + k] * M2 + O + oq * 4]);
        m.x = fmaxf(m.x, v.x); m.y = fmaxf(m.y, v.y);
        m.z = fmaxf(m.z, v.z); m.w = fmaxf(m.w, v.w);
    }
    const float4 b = *reinterpret_cast<const float4*>(&T[i * M2 + oq * 4]);
    const float4 bv = *reinterpret_cast<const float4*>(&bias[oq * 4]);
    float4 o;
    o.x = fmaxf(b.x + bv.x + m.x, 0.0f);
    o.y = fmaxf(b.y + bv.y + m.y, 0.0f);
    o.z = fmaxf(b.z + bv.z + m.z, 0.0f);
    o.w = fmaxf(b.w + bv.w + m.w, 0.0f);
    if (OUT_BF16) {
        const __hip_bfloat16 h0 = __float2bfloat16(o.x);
        const __hip_bfloat16 h1 = __float2bfloat16(o.y);
        const __hip_bfloat16 h2 = __float2bfloat16(o.z);
        const __hip_bfloat16 h3 = __float2bfloat16(o.w);
        ushort4 u;
        u.x = *reinterpret_cast<const ushort*>(&h0);
        u.y = *reinterpret_cast<const ushort*>(&h1);
        u.z = *reinterpret_cast<const ushort*>(&h2);
        u.w = *reinterpret_cast<const ushort*>(&h3);
        *reinterpret_cast<ushort4*>(reinterpret_cast<ushort*>(outv) + i * O + oq * 4) = u;
    } else {
        *reinterpret_cast<float4*>(reinterpret_cast<float*>(outv) + i * O + oq * 4) = o;
    }
}

extern "C" void kernel_launch(void* const* d_in, const int* in_sizes, int n_in,
                              void* d_out, int out_size, void* d_ws, size_t ws_size,
                              hipStream_t stream) {
    const float* x  = (const float*)d_in[0];
    const float* W0 = (const float*)d_in[1];
    const float* b0 = (const float*)d_in[2];
    const float* W1 = (const float*)d_in[3];
    const float* b1 = (const float*)d_in[4];
    const float* W2 = (const float*)d_in[5];
    const float* b2 = (const float*)d_in[6];
    float* out = (float*)d_out;
    char*  ws  = (char*)d_ws;

    int*            idx  = (int*)(ws + 0);                   // 655360
    float*          Wc0  = (float*)(ws + 655360);            // 1536
    __hip_bfloat16* Wc1  = (__hip_bfloat16*)(ws + 656896);   // 32 KB
    __hip_bfloat16* Wc2  = (__hip_bfloat16*)(ws + 722432);   // 128 KB
    float*          bufA = (float*)(ws + 984576);            // 16 MB (T: fp32)
    void*           bufB = (void*)(ws + 17761792);           // 4 MB (h: bf16)

    // knn-phase scratch aliases bufA (dead before gemm_bf16 writes bufA)
    float4* srt  = (float4*)((char*)bufA + 131072);          // 128 KB
    float4* bmin = (float4*)((char*)bufA + 442368);          // 2 KB
    float4* bmax = (float4*)((char*)bufA + 444416);          // 2 KB

    // whole pre-knn chain (sort + AABB + weight restructure) in one kernel
    sortall<<<9, 1024, 0, stream>>>(x, W0, W1, W2, srt, bmin, bmax, Wc0, Wc1, Wc2);
    knn_kernel<<<NPTS / 4, 256, 0, stream>>>(srt, bmin, bmax, idx);

    // layer 0 fused: x -> h0(8192x64 bf16) directly
    layer0_fused<<<NPTS / 16, 256, 0, stream>>>(x, Wc0, b0, idx, (ushort*)bufB);

    // layer 1: h0 -> T1(8192x256 f32) -> h1(8192x128 bf16)
    gemm_bf16<<<dim3(128, 4), 256, 0, stream>>>((const ushort*)bufB, (const ushort*)Wc1,
                                                bufA, 64, 256);
    maxrelu_kernel<128, 1><<<NPTS / 8, 256, 0, stream>>>(bufA, idx, b1, bufB);

    // layer 2: h1 -> T2(8192x512 f32) -> out(8192x256 f32)
    gemm_bf16<<<dim3(128, 8), 256, 0, stream>>>((const ushort*)bufB, (const ushort*)Wc2,
                                                bufA, 128, 512);
    maxrelu_kernel<256, 0><<<NPTS / 4, 256, 0, stream>>>(bufA, idx, b2, out);
}

// Round 16
// 89.296 us; speedup vs baseline: 1.8277x; 1.0801x over previous
//
#include <hip/hip_runtime.h>
#include <hip/hip_bf16.h>
#include <math.h>

#define NPTS 8192
#define KNN  20
#define NBLK (NPTS / 64)           // 128 sorted 64-blocks
#define NCELL 4096                 // 16^3 Morton cells
#define GLO  (-4.0f)
#define GINV (2.0f)

typedef __attribute__((ext_vector_type(8))) short short8v;
typedef __attribute__((ext_vector_type(4))) float f32x4v;

__device__ __forceinline__ int cellof(float v) {
    int c = (int)floorf((v - GLO) * GINV);
    return min(max(c, 0), 15);
}
__device__ __forceinline__ int spread4(int b) {
    return (b & 1) | ((b & 2) << 2) | ((b & 4) << 4) | ((b & 8) << 6);
}
// orderable encoding: unsigned compare == float compare
__device__ __forceinline__ unsigned fenc(float f) {
    unsigned u = __float_as_uint(f);
    return (u & 0x80000000u) ? ~u : (u | 0x80000000u);
}
__device__ __forceinline__ float fdec(unsigned k) {
    unsigned u = (k & 0x80000000u) ? (k & 0x7fffffffu) : ~k;
    return __uint_as_float(u);
}

// 64-lane bitonic sort, ascending by lane. Keys d, payload ji.
__device__ __forceinline__ void bitonic64(float& d, int& ji, int lane) {
#pragma unroll
    for (int k = 2; k <= 64; k <<= 1) {
#pragma unroll
        for (int j = k >> 1; j > 0; j >>= 1) {
            const float od = __shfl_xor(d, j);
            const int   oi = __shfl_xor(ji, j);
            const bool up      = ((lane & k) == 0);
            const bool lower   = ((lane & j) == 0);
            const bool takeMin = (up == lower);
            const bool sw = takeMin ? (od < d) : (od > d);
            d  = sw ? od : d;
            ji = sw ? oi : ji;
        }
    }
}

__device__ __forceinline__ void bitonic_clean64(float& d, int& ji, int lane) {
#pragma unroll
    for (int j = 32; j > 0; j >>= 1) {
        const float od = __shfl_xor(d, j);
        const int   oi = __shfl_xor(ji, j);
        const bool lower = ((lane & j) == 0);
        const bool sw = lower ? (od < d) : (od > d);
        d  = sw ? od : d;
        ji = sw ? oi : ji;
    }
}

// merge LDS hit-pool (cnt entries) into the resident sorted-64 list (ld,lj)
__device__ __forceinline__ void compact(float& ld, int& lj,
                                        const float* __restrict__ sd,
                                        const int* __restrict__ sj,
                                        int cnt, int lane) {
    __builtin_amdgcn_wave_barrier();          // order pool ds_writes before reads
    float bd = (lane < cnt) ? sd[lane] : INFINITY;
    int   bj = (lane < cnt) ? sj[lane] : -1;
    bitonic64(bd, bj, lane);
    const float rd = __shfl(bd, 63 - lane);
    const int   rj = __shfl(bj, 63 - lane);
    const bool sw = rd < ld;
    float md = sw ? rd : ld;
    int   mj = sw ? rj : lj;
    bitonic_clean64(md, mj, lane);
    ld = md; lj = mj;
}

// ---------------- weight restructure helpers ----------------
__device__ __forceinline__ void prep_w_elem(const float* __restrict__ W,
                                            float* __restrict__ Wc,
                                            int tid, int O, int C) {
    const int o = tid / C, k = tid % C;
    const float wa = W[o*2*C + k];
    const float wb = W[o*2*C + C + k];
    Wc[o*C + k]       = wa - wb;
    Wc[(O + o)*C + k] = wb;
}

__device__ __forceinline__ void prep_w_elem_b(const float* __restrict__ W,
                                              __hip_bfloat16* __restrict__ Wc,
                                              int tid, int O, int C) {
    const int o = tid / C, k = tid % C;
    const float wa = W[o*2*C + k];
    const float wb = W[o*2*C + C + k];
    Wc[o*C + k]       = __float2bfloat16(wa - wb);
    Wc[(O + o)*C + k] = __float2bfloat16(wb);
}

// ---------------- sortall: whole pre-knn chain in ONE kernel ----------------
__global__ __launch_bounds__(1024) void sortall(const float* __restrict__ x,
                                                const float* __restrict__ W0,
                                                const float* __restrict__ W1,
                                                const float* __restrict__ W2,
                                                float4* __restrict__ srt,
                                                float4* __restrict__ bming,
                                                float4* __restrict__ bmaxg,
                                                float* __restrict__ Wc0,
                                                __hip_bfloat16* __restrict__ Wc1,
                                                __hip_bfloat16* __restrict__ Wc2) {
    const int t = threadIdx.x;
    if (blockIdx.x != 0) {
        for (int g = (blockIdx.x - 1) * 1024 + t; g < 192 + 8192 + 32768; g += 8 * 1024) {
            if (g < 192)             prep_w_elem(W0, Wc0, g, 64, 3);
            else if (g < 192 + 8192) prep_w_elem_b(W1, Wc1, g - 192, 128, 64);
            else                     prep_w_elem_b(W2, Wc2, g - 8384, 256, 128);
        }
        return;
    }
    __shared__ int lh[NCELL];
    __shared__ int lw[NCELL];
    __shared__ int ls[1024];
    __shared__ unsigned abn[NBLK * 3], abx[NBLK * 3];

    float px[8], py[8], pz[8];
    int   pc[8];
    for (int u = t; u < NCELL; u += 1024) { lh[u] = 0; }
    for (int u = t; u < NBLK * 3; u += 1024) { abn[u] = 0xFFFFFFFFu; abx[u] = 0u; }
    __syncthreads();
#pragma unroll
    for (int u = 0; u < 8; ++u) {
        const int i = u * 1024 + t;
        const float a = x[3*i+0], b = x[3*i+1], c = x[3*i+2];
        px[u] = a; py[u] = b; pz[u] = c;
        pc[u] = spread4(cellof(a)) | (spread4(cellof(b)) << 1) | (spread4(cellof(c)) << 2);
        atomicAdd(&lh[pc[u]], 1);
    }
    __syncthreads();
    const int h0 = lh[4*t+0], h1 = lh[4*t+1], h2 = lh[4*t+2], h3 = lh[4*t+3];
    const int s0 = h0, s1 = s0 + h1, s2 = s1 + h2, s3 = s2 + h3;
    ls[t] = s3;
    __syncthreads();
    for (int off = 1; off < 1024; off <<= 1) {
        const int uu = (t >= off) ? ls[t - off] : 0;
        __syncthreads();
        ls[t] += uu;
        __syncthreads();
    }
    const int excl = ls[t] - s3;
    lw[4*t+0] = excl;      lw[4*t+1] = excl + s0;
    lw[4*t+2] = excl + s1; lw[4*t+3] = excl + s2;
    __syncthreads();
#pragma unroll
    for (int u = 0; u < 8; ++u) {
        const int i = u * 1024 + t;
        const int pos = atomicAdd(&lw[pc[u]], 1);
        srt[pos] = make_float4(px[u], py[u], pz[u], __int_as_float(i));
        const int blk = pos >> 6;
        atomicMin(&abn[blk*3+0], fenc(px[u])); atomicMax(&abx[blk*3+0], fenc(px[u]));
        atomicMin(&abn[blk*3+1], fenc(py[u])); atomicMax(&abx[blk*3+1], fenc(py[u]));
        atomicMin(&abn[blk*3+2], fenc(pz[u])); atomicMax(&abx[blk*3+2], fenc(pz[u]));
    }
    __syncthreads();
    if (t < NBLK) {
        bming[t] = make_float4(fdec(abn[3*t+0]), fdec(abn[3*t+1]), fdec(abn[3*t+2]), 0.0f);
        bmaxg[t] = make_float4(fdec(abx[3*t+0]), fdec(abx[3*t+1]), fdec(abx[3*t+2]), 0.0f);
    }
}

// ---------------- KNN + fused layer-0 ----------------
// Morton init + prefetched near-first window pre-pass + 2-deep AABB scan,
// then epilogue computes h0 = relu(base + max_k xj.Wb) directly from the
// in-register neighbor list (saves the layer0 dispatch + idx/coord re-reads).
__global__ __launch_bounds__(256) void knn_kernel(const float4* __restrict__ srt,
                                                  const float4* __restrict__ bmin,
                                                  const float4* __restrict__ bmax,
                                                  const float* __restrict__ x,
                                                  const float* __restrict__ Wc0,
                                                  const float* __restrict__ b0,
                                                  int* __restrict__ idx_out,
                                                  ushort* __restrict__ h0out) {
    __shared__ float sdp[4][64];
    __shared__ int   sjp[4][64];
    const int lane = threadIdx.x & 63;
    const int wv   = threadIdx.x >> 6;
    const int s    = blockIdx.x * 4 + wv;
    float* sd = sdp[wv];
    int*   sj = sjp[wv];

    const float4 p = srt[s];
    const int qorig = __float_as_int(p.w);
    const int bq = s >> 6;
    const int wlo = max(bq - 3, 0);
    const int whi = min(bq + 3, NBLK - 1);

    // prefetch: own block + all 6 window blocks issued together (MLP=7),
    // NEAR-FIRST order so cm tightens fastest during the pre-pass.
    const float4 own = srt[(bq << 6) + lane];
    float4 wb[6];
    bool   wvalid[6];
    const int woff[6] = {1, -1, 2, -2, 3, -3};
#pragma unroll
    for (int j = 0; j < 6; ++j) {
        const int bb = bq + woff[j];
        wvalid[j] = (bb >= 0) && (bb < NBLK);
        const int bc = min(max(bb, 0), NBLK - 1);
        wb[j] = srt[(bc << 6) + lane];
    }

    // init: own Morton block (contains self, d=0 -> lane 0 after final sort)
    float ld, cm;
    int lj;
    {
        const float dx = p.x - own.x, dy = p.y - own.y, dz = p.z - own.z;
        ld = dx*dx + dy*dy + dz*dz;
        lj = __float_as_int(own.w);
        bitonic64(ld, lj, lane);
        cm = __shfl(ld, KNN);                 // 21st incl self = 20th excl
    }
    int cnt = 0;

#define APPEND(M, D, C4)                                                      \
    if (M) {                                                                  \
        const int tot = __popcll(M);                                          \
        if (cnt + tot > 64) {                                                 \
            compact(ld, lj, sd, sj, cnt, lane);                               \
            cm = __shfl(ld, KNN);                                             \
            cnt = 0;                                                          \
        }                                                                     \
        const int below = __builtin_amdgcn_mbcnt_hi(                          \
            (unsigned)((M) >> 32),                                            \
            __builtin_amdgcn_mbcnt_lo((unsigned)(M), 0));                     \
        const bool h = ((M) >> lane) & 1ull;                                  \
        if (h) { sd[cnt + below] = D; sj[cnt + below] = __float_as_int(C4.w); } \
        cnt += tot;                                                           \
    }

    // pre-pass over prefetched window blocks (no serial load latency)
#pragma unroll
    for (int j = 0; j < 6; ++j) {
        const float dx = p.x - wb[j].x, dy = p.y - wb[j].y, dz = p.z - wb[j].z;
        const float d = dx*dx + dy*dy + dz*dz;
        const unsigned long long m = __ballot(wvalid[j] && (d < cm));
        APPEND(m, d, wb[j])
    }
    if (cnt > 0) { compact(ld, lj, sd, sj, cnt, lane); cm = __shfl(ld, KNN); cnt = 0; }

    // AABB screen: lane handles blocks lane and lane+64
    unsigned long long mlo, mhi;
    {
        const float4 n0 = bmin[lane],      x0 = bmax[lane];
        const float4 n1 = bmin[lane + 64], x1 = bmax[lane + 64];
        float ax = fmaxf(fmaxf(n0.x - p.x, p.x - x0.x), 0.0f);
        float ay = fmaxf(fmaxf(n0.y - p.y, p.y - x0.y), 0.0f);
        float az = fmaxf(fmaxf(n0.z - p.z, p.z - x0.z), 0.0f);
        const float lb0 = ax*ax + ay*ay + az*az;
        ax = fmaxf(fmaxf(n1.x - p.x, p.x - x1.x), 0.0f);
        ay = fmaxf(fmaxf(n1.y - p.y, p.y - x1.y), 0.0f);
        az = fmaxf(fmaxf(n1.z - p.z, p.z - x1.z), 0.0f);
        const float lb1 = ax*ax + ay*ay + az*az;
        const bool h0 = (lb0 < cm) && (lane < wlo || lane > whi);
        const bool h1 = (lb1 < cm) && (lane + 64 < wlo || lane + 64 > whi);
        mlo = __ballot(h0);
        mhi = __ballot(h1);
    }

    // 2-deep pipelined scan of selected blocks
    while (mlo | mhi) {
        int bb0;
        if (mlo) { bb0 = __ffsll(mlo) - 1;      mlo &= (mlo - 1); }
        else     { bb0 = 64 + __ffsll(mhi) - 1; mhi &= (mhi - 1); }
        const bool has1 = (mlo | mhi) != 0;
        int bb1 = bb0;
        if (has1) {
            if (mlo) { bb1 = __ffsll(mlo) - 1;      mlo &= (mlo - 1); }
            else     { bb1 = 64 + __ffsll(mhi) - 1; mhi &= (mhi - 1); }
        }
        const float4 c0 = srt[(bb0 << 6) + lane];
        const float4 c1 = srt[(bb1 << 6) + lane];
        const float dx0 = p.x - c0.x, dy0 = p.y - c0.y, dz0 = p.z - c0.z;
        const float d0 = dx0*dx0 + dy0*dy0 + dz0*dz0;
        const float dx1 = p.x - c1.x, dy1 = p.y - c1.y, dz1 = p.z - c1.z;
        const float d1 = dx1*dx1 + dy1*dy1 + dz1*dz1;
        const unsigned long long m0 = __ballot(d0 < cm);
        APPEND(m0, d0, c0)
        const unsigned long long m1 = __ballot(has1 && (d1 < cm));
        APPEND(m1, d1, c1)
    }
    if (cnt > 0) compact(ld, lj, sd, sj, cnt, lane);
#undef APPEND

    if (lane >= 1 && lane <= KNN) idx_out[qorig * KNN + lane - 1] = lj;

    // ---- fused layer 0: h0[qorig][lane] = relu(xi.Wa-b + b0 + max_k xj.Wb) ----
    {
        // gather 60 neighbor-coord floats, one per lane (lanes 0..59)
        const int nk = lane / 3;              // neighbor slot 0..19 (lanes<60)
        const int c  = lane % 3;
        const int nj = __shfl(lj, 1 + nk);    // neighbor original id
        float v = 0.0f;
        if (lane < 60) v = x[3 * nj + c];
        __builtin_amdgcn_wave_barrier();      // pool reads (compact) done
        sd[lane] = v;
        __builtin_amdgcn_wave_barrier();
        // channel o = lane
        const float w0 = Wc0[3 * lane + 0];   // rows 0..63: Wa - Wb
        const float w1 = Wc0[3 * lane + 1];
        const float w2 = Wc0[3 * lane + 2];
        const float u0 = Wc0[3 * (64 + lane) + 0];  // rows 64..127: Wb
        const float u1 = Wc0[3 * (64 + lane) + 1];
        const float u2 = Wc0[3 * (64 + lane) + 2];
        const float base = p.x * w0 + p.y * w1 + p.z * w2 + b0[lane];
        float m = -INFINITY;
#pragma unroll
        for (int k = 0; k < KNN; ++k) {
            const float xj0 = sd[3*k+0], xj1 = sd[3*k+1], xj2 = sd[3*k+2];
            m = fmaxf(m, xj0*u0 + xj1*u1 + xj2*u2);
        }
        const float o = fmaxf(base + m, 0.0f);
        const __hip_bfloat16 hb = __float2bfloat16(o);
        h0out[qorig * 64 + lane] = *reinterpret_cast<const ushort*>(&hb);
    }
}

// ---------------- bf16 MFMA GEMM: T(f32) = H(bf16, NxK) * Wc^T(bf16, MxK) ----------------
__global__ __launch_bounds__(256) void gemm_bf16(const ushort* __restrict__ H,
                                                 const ushort* __restrict__ Wc,
                                                 float* __restrict__ T,
                                                 int Kk, int Mm) {
    const int l  = threadIdx.x & 63;
    const int w  = threadIdx.x >> 6;
    const int m  = l & 15;
    const int kg = l >> 4;
    const int row_t = blockIdx.x * 64 + w * 16;
    const int col0  = blockIdx.y * 64;

    f32x4v acc0 = {0.f, 0.f, 0.f, 0.f};
    f32x4v acc1 = acc0, acc2 = acc0, acc3 = acc0;

    const ushort* hp = H  + (row_t + m) * Kk + kg * 8;
    const ushort* wp = Wc + (col0 + m) * Kk + kg * 8;
    const int wstep = 16 * Kk;

    for (int k0 = 0; k0 < Kk; k0 += 32) {
        const short8v a  = *reinterpret_cast<const short8v*>(hp + k0);
        const short8v b0 = *reinterpret_cast<const short8v*>(wp + k0);
        const short8v b1 = *reinterpret_cast<const short8v*>(wp + wstep + k0);
        const short8v b2 = *reinterpret_cast<const short8v*>(wp + 2 * wstep + k0);
        const short8v b3 = *reinterpret_cast<const short8v*>(wp + 3 * wstep + k0);
        acc0 = __builtin_amdgcn_mfma_f32_16x16x32_bf16(a, b0, acc0, 0, 0, 0);
        acc1 = __builtin_amdgcn_mfma_f32_16x16x32_bf16(a, b1, acc1, 0, 0, 0);
        acc2 = __builtin_amdgcn_mfma_f32_16x16x32_bf16(a, b2, acc2, 0, 0, 0);
        acc3 = __builtin_amdgcn_mfma_f32_16x16x32_bf16(a, b3, acc3, 0, 0, 0);
    }

    const int orow = row_t + kg * 4;
#pragma unroll
    for (int r = 0; r < 4; ++r) {
        float* trow = &T[(orow + r) * Mm + col0 + m];
        trow[0]  = acc0[r];
        trow[16] = acc1[r];
        trow[32] = acc2[r];
        trow[48] = acc3[r];
    }
}

// ---------------- gather + max + bias + relu (float4/thread, optional bf16 out) ----------------
template<int O, int OUT_BF16>
__global__ __launch_bounds__(256) void maxrelu_kernel(const float* __restrict__ T,
                                                      const int* __restrict__ idx,
                                                      const float* __restrict__ bias,
                                                      void* __restrict__ outv) {
    constexpr int Q   = O / 4;
    constexpr int PPB = 256 / Q;
    constexpr int M2  = 2 * O;
    const int pi = threadIdx.x / Q;
    const int oq = threadIdx.x & (Q - 1);
    const int i  = blockIdx.x * PPB + pi;
    __shared__ int sidx[PPB * KNN];
    for (int t = threadIdx.x; t < PPB * KNN; t += 256)
        sidx[t] = idx[blockIdx.x * PPB * KNN + t];
    __syncthreads();
    const int sb = pi * KNN;
    float4 m = make_float4(-INFINITY, -INFINITY, -INFINITY, -INFINITY);
#pragma unroll
    for (int k = 0; k < KNN; ++k) {
        const float4 v = *reinterpret_cast<const float4*>(&T[sidx[sb + k] * M2 + O + oq * 4]);
        m.x = fmaxf(m.x, v.x); m.y = fmaxf(m.y, v.y);
        m.z = fmaxf(m.z, v.z); m.w = fmaxf(m.w, v.w);
    }
    const float4 b = *reinterpret_cast<const float4*>(&T[i * M2 + oq * 4]);
    const float4 bv = *reinterpret_cast<const float4*>(&bias[oq * 4]);
    float4 o;
    o.x = fmaxf(b.x + bv.x + m.x, 0.0f);
    o.y = fmaxf(b.y + bv.y + m.y, 0.0f);
    o.z = fmaxf(b.z + bv.z + m.z, 0.0f);
    o.w = fmaxf(b.w + bv.w + m.w, 0.0f);
    if (OUT_BF16) {
        const __hip_bfloat16 h0 = __float2bfloat16(o.x);
        const __hip_bfloat16 h1 = __float2bfloat16(o.y);
        const __hip_bfloat16 h2 = __float2bfloat16(o.z);
        const __hip_bfloat16 h3 = __float2bfloat16(o.w);
        ushort4 u;
        u.x = *reinterpret_cast<const ushort*>(&h0);
        u.y = *reinterpret_cast<const ushort*>(&h1);
        u.z = *reinterpret_cast<const ushort*>(&h2);
        u.w = *reinterpret_cast<const ushort*>(&h3);
        *reinterpret_cast<ushort4*>(reinterpret_cast<ushort*>(outv) + i * O + oq * 4) = u;
    } else {
        *reinterpret_cast<float4*>(reinterpret_cast<float*>(outv) + i * O + oq * 4) = o;
    }
}

extern "C" void kernel_launch(void* const* d_in, const int* in_sizes, int n_in,
                              void* d_out, int out_size, void* d_ws, size_t ws_size,
                              hipStream_t stream) {
    const float* x  = (const float*)d_in[0];
    const float* W0 = (const float*)d_in[1];
    const float* b0 = (const float*)d_in[2];
    const float* W1 = (const float*)d_in[3];
    const float* b1 = (const float*)d_in[4];
    const float* W2 = (const float*)d_in[5];
    const float* b2 = (const float*)d_in[6];
    float* out = (float*)d_out;
    char*  ws  = (char*)d_ws;

    int*            idx  = (int*)(ws + 0);                   // 655360
    float*          Wc0  = (float*)(ws + 655360);            // 1536
    __hip_bfloat16* Wc1  = (__hip_bfloat16*)(ws + 656896);   // 32 KB
    __hip_bfloat16* Wc2  = (__hip_bfloat16*)(ws + 722432);   // 128 KB
    float*          bufA = (float*)(ws + 984576);            // 16 MB (T: fp32)
    void*           bufB = (void*)(ws + 17761792);           // 4 MB (h: bf16)

    // knn-phase scratch aliases bufA (dead before gemm_bf16 writes bufA)
    float4* srt  = (float4*)((char*)bufA + 131072);          // 128 KB
    float4* bmin = (float4*)((char*)bufA + 442368);          // 2 KB
    float4* bmax = (float4*)((char*)bufA + 444416);          // 2 KB

    // whole pre-knn chain (sort + AABB + weight restructure) in one kernel
    sortall<<<9, 1024, 0, stream>>>(x, W0, W1, W2, srt, bmin, bmax, Wc0, Wc1, Wc2);

    // knn + fused layer 0: idx + h0(8192x64 bf16) in one kernel
    knn_kernel<<<NPTS / 4, 256, 0, stream>>>(srt, bmin, bmax, x, Wc0, b0,
                                             idx, (ushort*)bufB);

    // layer 1: h0 -> T1(8192x256 f32) -> h1(8192x128 bf16)
    gemm_bf16<<<dim3(128, 4), 256, 0, stream>>>((const ushort*)bufB, (const ushort*)Wc1,
                                                bufA, 64, 256);
    maxrelu_kernel<128, 1><<<NPTS / 8, 256, 0, stream>>>(bufA, idx, b1, bufB);

    // layer 2: h1 -> T2(8192x512 f32) -> out(8192x256 f32)
    gemm_bf16<<<dim3(128, 8), 256, 0, stream>>>((const ushort*)bufB, (const ushort*)Wc2,
                                                bufA, 128, 512);
    maxrelu_kernel<256, 0><<<NPTS / 4, 256, 0, stream>>>(bufA, idx, b2, out);
}